// Round 3
// baseline (435.432 us; speedup 1.0000x reference)
//
#include <hip/hip_runtime.h>

#define N_ROWS 100000
#define M_NBR  12
#define C_DIM  64
#define F_DIM  41
#define E_TOT  (N_ROWS * M_NBR)

// ---------------------------------------------------------------------------
// Kernel A: s_e = (softplus(x_e @ W1 + b1) . w2[:,0] + b2[0]) * c
//
// vs round 2: VGPR_Count=44 proved the compiler was INTERCHANGING the loops
// (h[j] computed one at a time), which turns w1 access column-strided ->
// 1681 single s_load_dwords per wave -> scalar-pipe bound (~51us/CU issue
// + lgkmcnt(0) drains). Fix: pin ALL h[j] in VGPRs at the end of every
// k-iteration. Interchange becomes impossible; w1 is consumed row-wise
// (s_load_dwordx8 x5 per row, 246 loads/wave) and row k+1's loads issue
// under row k's 82-cycle FMA run.
// ---------------------------------------------------------------------------
__global__ __launch_bounds__(256) void edge_mlp_kernel(
    const float* __restrict__ nbr_fea,   // [E, F]
    const float* __restrict__ w1,        // [F, F]
    const float* __restrict__ b1,        // [F]
    const float* __restrict__ w2,        // [F, 9]
    const float* __restrict__ b2,        // [9]
    float* __restrict__ s_out)           // [E]
{
    __shared__ float lx[128 * F_DIM];    // 20992 B

    const int tid  = threadIdx.x;
    const long base = (long)blockIdx.x * 256;
    int rem = (int)((long)E_TOT - base);
    const int nedge = rem < 256 ? rem : 256;

    float x[F_DIM];

    // ---- phase 0: stage rows [0,128), threads 0..127 copy their row to regs
    {
        const int cnt = nedge < 128 ? nedge : 128;
        const float* gx = nbr_fea + base * F_DIM;
        const int totf  = cnt * F_DIM;
        const int tot4  = totf >> 2;                 // 16B-aligned (base%256==0)
        const float4* g4 = (const float4*)gx;
        float4* l4 = (float4*)lx;
        for (int i = tid; i < tot4; i += 256) l4[i] = g4[i];
        for (int i = (tot4 << 2) + tid; i < totf; i += 256) lx[i] = gx[i];
        __syncthreads();
        if (tid < cnt) {
            #pragma unroll
            for (int k = 0; k < F_DIM; ++k) x[k] = lx[tid * F_DIM + k];  // stride 41: conflict-free
        }
        __syncthreads();
    }
    // ---- phase 1: stage rows [128,256), threads 128..255 copy to regs
    {
        const int cnt = nedge - 128 < 0 ? 0 : nedge - 128;
        const float* gx = nbr_fea + (base + 128) * F_DIM;   // +20992 B: 16B-aligned
        const int totf  = cnt * F_DIM;
        const int tot4  = totf >> 2;
        const float4* g4 = (const float4*)gx;
        float4* l4 = (float4*)lx;
        for (int i = tid; i < tot4; i += 256) l4[i] = g4[i];
        for (int i = (tot4 << 2) + tid; i < totf; i += 256) lx[i] = gx[i];
        __syncthreads();
        if (tid >= 128 && (tid - 128) < cnt) {
            #pragma unroll
            for (int k = 0; k < F_DIM; ++k) x[k] = lx[(tid - 128) * F_DIM + k];
        }
        __syncthreads();
    }

    if (tid < nedge) {
        // Pin x[] into VGPRs: all ds_reads resolve before the compute loop.
        #pragma unroll
        for (int k = 0; k < F_DIM; ++k) asm volatile("" : "+v"(x[k]));

        float h[F_DIM];
        #pragma unroll
        for (int j = 0; j < F_DIM; ++j) h[j] = b1[j];          // scalar loads

        #pragma unroll
        for (int k = 0; k < F_DIM; ++k) {
            const float xk = x[k];
            const float* wrow = w1 + k * F_DIM;                // uniform addr -> s_load_dwordx8 (row-contiguous)
            #pragma unroll
            for (int j = 0; j < F_DIM; ++j) h[j] = fmaf(xk, wrow[j], h[j]);
            // Pin ALL h[j] each k: loop interchange impossible; forces
            // k-outer with h resident in 41 VGPRs.
            #pragma unroll
            for (int j = 0; j < F_DIM; ++j) asm volatile("" : "+v"(h[j]));
        }

        float acc = b2[0];
        #pragma unroll
        for (int j = 0; j < F_DIM; ++j) {
            float v = h[j];
            float sp = fmaxf(v, 0.0f) + __logf(1.0f + __expf(-fabsf(v)));
            acc = fmaf(sp, w2[j * 9], acc);                    // w2 col 0, scalar loads
        }
        s_out[base + tid] = acc * (0.28209479177387814f / 12.0f);
    }
}

// ---------------------------------------------------------------------------
// Kernel B1: afT = atom_fea @ (tp_w / 8).  Stage 64 rows coalesced into LDS,
// then wave-uniform ds_read_b128 broadcast reads vs per-lane Tc[64] in VGPRs.
// (Unchanged from round 2 — its counters surface next round once A drops.)
// ---------------------------------------------------------------------------
__global__ __launch_bounds__(256) void atom_transform_kernel(
    const float* __restrict__ atom_fea,  // [N, C]
    const float* __restrict__ tp_w,      // [C, C]
    float* __restrict__ afT)             // [N, C]
{
    __shared__ float sA[64 * C_DIM];     // 16 KB: 64 atom rows

    const int tid = threadIdx.x;
    const int c   = tid & 63;
    const int wv  = tid >> 6;

    float Tc[64];
    #pragma unroll
    for (int k = 0; k < 64; ++k) Tc[k] = tp_w[k * 64 + c] * 0.125f;  // coalesced

    const long row0 = (long)blockIdx.x * 64;
    long nrem = (long)N_ROWS - row0;
    const int nrow = nrem < 64 ? (int)nrem : 64;

    // stage nrow rows coalesced: nrow*64 floats, float4 x (nrow*16)
    {
        const float4* g4 = (const float4*)(atom_fea + row0 * C_DIM);
        float4* l4 = (float4*)sA;
        const int tot4 = nrow * 16;
        for (int i = tid; i < tot4; i += 256) l4[i] = g4[i];
    }
    __syncthreads();

    const int r0 = wv * 16;
    for (int i = 0; i < 16; ++i) {
        int rl = r0 + i;                              // wave-uniform
        if (rl >= nrow) break;
        const float4* ar = (const float4*)(sA + rl * C_DIM);   // uniform addr -> ds broadcast
        float o = 0.0f;
        #pragma unroll
        for (int k4 = 0; k4 < 16; ++k4) {
            float4 a = ar[k4];                        // ds_read_b128, broadcast
            o = fmaf(a.x, Tc[4 * k4 + 0], o);
            o = fmaf(a.y, Tc[4 * k4 + 1], o);
            o = fmaf(a.z, Tc[4 * k4 + 2], o);
            o = fmaf(a.w, Tc[4 * k4 + 3], o);
        }
        afT[(row0 + rl) * C_DIM + c] = o;             // coalesced
    }
}

// ---------------------------------------------------------------------------
// Kernel B2: out[r][:] = sum_j s_rj * afT[idx_rj][:].  Pure gather + 12 FMA,
// float4 per lane, 4 rows in flight per wave, no LDS.  (Unchanged.)
// ---------------------------------------------------------------------------
__global__ __launch_bounds__(256) void gather_kernel(
    const float* __restrict__ afT,       // [N, C]
    const int*   __restrict__ nbr_idx,   // [N, M]
    const float* __restrict__ s,         // [E]
    float* __restrict__ out)             // [N, C]
{
    const int tid  = threadIdx.x;
    const int lane = tid & 63;
    const int wv   = tid >> 6;
    const int q    = lane >> 4;          // row-in-chunk 0..3
    const int c4   = (lane & 15) * 4;    // channel offset

    const int row0 = blockIdx.x * 32 + wv * 8;   // 8 rows per wave (N = 3125*32)

    #pragma unroll
    for (int ch = 0; ch < 2; ++ch) {
        int r = row0 + ch * 4 + q;
        const int*   ir = nbr_idx + r * M_NBR;
        const float* sr = s       + r * M_NBR;
        float4 acc = make_float4(0.f, 0.f, 0.f, 0.f);
        #pragma unroll
        for (int j = 0; j < M_NBR; ++j) {
            int   idx = ir[j];
            float sv  = sr[j];
            const float4 a = *(const float4*)(afT + (long)idx * C_DIM + c4);
            acc.x = fmaf(sv, a.x, acc.x);
            acc.y = fmaf(sv, a.y, acc.y);
            acc.z = fmaf(sv, a.z, acc.z);
            acc.w = fmaf(sv, a.w, acc.w);
        }
        *(float4*)(out + (long)r * C_DIM + c4) = acc;   // coalesced
    }
}

// ---------------------------------------------------------------------------
// Fallback (ws too small for afT): fused gather + LDS-epilogue transform.
// ---------------------------------------------------------------------------
__global__ __launch_bounds__(256) void gather_transform_kernel(
    const float* __restrict__ atom_fea,
    const int*   __restrict__ nbr_idx,
    const float* __restrict__ s,
    const float* __restrict__ tp_w,
    float* __restrict__ out)
{
    __shared__ float accL[64 * C_DIM];
    const int tid = threadIdx.x;
    const int c  = tid & 63;
    const int rq = tid >> 6;

    float Tc[64];
    #pragma unroll
    for (int k = 0; k < 64; ++k) Tc[k] = tp_w[k * 64 + c] * 0.125f;

    const int row0 = blockIdx.x * 64;
    for (int i = 0; i < 16; ++i) {
        int r = row0 + rq * 16 + i;
        float a = 0.0f;
        if (r < N_ROWS) {
            const int*   ir = nbr_idx + (long)r * M_NBR;
            const float* sr = s       + (long)r * M_NBR;
            #pragma unroll
            for (int j = 0; j < M_NBR; ++j)
                a = fmaf(sr[j], atom_fea[(long)ir[j] * C_DIM + c], a);
        }
        accL[(rq * 16 + i) * C_DIM + c] = a;
    }
    __syncthreads();
    for (int i = 0; i < 16; ++i) {
        int rl = rq * 16 + i;
        int r  = row0 + rl;
        if (r >= N_ROWS) continue;
        const float* ar = accL + rl * C_DIM;
        float o = 0.0f;
        #pragma unroll
        for (int k = 0; k < 64; ++k) o = fmaf(ar[k], Tc[k], o);
        out[(long)r * C_DIM + c] = o;
    }
}

extern "C" void kernel_launch(void* const* d_in, const int* in_sizes, int n_in,
                              void* d_out, int out_size, void* d_ws, size_t ws_size,
                              hipStream_t stream) {
    const float* atom_fea = (const float*)d_in[0];
    const float* nbr_fea  = (const float*)d_in[1];
    const int*   nbr_idx  = (const int*)  d_in[2];
    // d_in[3] = pos : dead (only the constant l=0 SH channel couples)
    const float* w1   = (const float*)d_in[4];
    const float* b1   = (const float*)d_in[5];
    const float* w2   = (const float*)d_in[6];
    const float* b2   = (const float*)d_in[7];
    const float* tp_w = (const float*)d_in[8];

    float* s   = (float*)d_ws;                       // 4.8 MB
    float* out = (float*)d_out;

    const int blocksA = (E_TOT + 255) / 256;
    edge_mlp_kernel<<<blocksA, 256, 0, stream>>>(nbr_fea, w1, b1, w2, b2, s);

    const size_t sBytes   = (size_t)E_TOT * sizeof(float);          // 4,800,000 (16B-mult)
    const size_t afTBytes = (size_t)N_ROWS * C_DIM * sizeof(float); // 25.6 MB

    if (ws_size >= sBytes + afTBytes) {
        float* afT = (float*)((char*)d_ws + sBytes);
        const int blocksT = (N_ROWS + 63) / 64;
        atom_transform_kernel<<<blocksT, 256, 0, stream>>>(atom_fea, tp_w, afT);
        const int blocksG = N_ROWS / 32;             // 3125, exact
        gather_kernel<<<blocksG, 256, 0, stream>>>(afT, nbr_idx, s, out);
    } else {
        const int blocksB = (N_ROWS + 63) / 64;
        gather_transform_kernel<<<blocksB, 256, 0, stream>>>(atom_fea, nbr_idx, s, tp_w, out);
    }
}

// Round 4
// 406.243 us; speedup vs baseline: 1.0719x; 1.0719x over previous
//
#include <hip/hip_runtime.h>

#define N_ROWS 100000
#define M_NBR  12
#define C_DIM  64
#define F_DIM  41
#define E_TOT  (N_ROWS * M_NBR)

typedef _Float16 half8 __attribute__((ext_vector_type(8)));
typedef float float4v __attribute__((ext_vector_type(4)));

#define WPITCH 72   // _Float16 elems per row: 144B, keeps ds_read_b128 16B-aligned

// ---------------------------------------------------------------------------
// Kernel A (MFMA): s_e = (softplus(x_e @ W1 + b1) . w2[:,0] + b2[0]) * c
//
// Rounds 1-3 showed the compiler always collapses the VALU GEMM to a 44-VGPR
// interchanged form (scalar-pipe bound, 135-145us, VALUBusy ~55%). Fix: move
// the GEMM to the matrix pipe. fp16 Dekker split (x=xh+xl, W=wh+wl; 4 MFMA
// terms) keeps error ~2^-22 per operand -> no accuracy change vs fp32.
//   wave  = 64 edges x 48 outputs (N 41->48, K 41->64 zero-padded)
//   W^T hi/lo staged once per block in LDS (13.8 KB); B-frags (12 x 16B)
//   loaded once, register-resident. A-frags per-lane from global (bytes
//   fully consumed -> no overfetch). Epilogue: softplus + w2-dot +
//   16-lane shfl_xor butterfly reduce.
// ---------------------------------------------------------------------------
__global__ __launch_bounds__(256) void edge_mlp_mfma_kernel(
    const float* __restrict__ nbr_fea,   // [E, F]
    const float* __restrict__ w1,        // [F, F]
    const float* __restrict__ b1,        // [F]
    const float* __restrict__ w2,        // [F, 9]
    const float* __restrict__ b2,        // [9]
    float* __restrict__ s_out)           // [E]
{
    __shared__ _Float16 Wh[48 * WPITCH];   // 6912 B
    __shared__ _Float16 Wl[48 * WPITCH];   // 6912 B

    const int tid = threadIdx.x;

    // ---- build W^T padded [48 j][64 k], fp16 hi/lo split (once per block)
    for (int idx = tid; idx < 48 * 64; idx += 256) {
        const int j = idx >> 6, k = idx & 63;
        const float v = (j < F_DIM && k < F_DIM) ? w1[k * F_DIM + j] : 0.0f;
        const _Float16 vh = (_Float16)v;
        Wh[j * WPITCH + k] = vh;
        Wl[j * WPITCH + k] = (_Float16)(v - (float)vh);   // exact residual in fp32
    }
    __syncthreads();

    const int lane = tid & 63;
    const int wv   = tid >> 6;
    const int n15  = lane & 15;          // A-row / B-col / C-col index
    const int g    = lane >> 4;          // k-group (A/B), row-group (C)

    // ---- B fragments: register-resident for the whole kernel
    half8 Bh[3][2], Bl[3][2];            // [ntile][kstep]
    #pragma unroll
    for (int nt = 0; nt < 3; ++nt) {
        const int j = nt * 16 + n15;
        #pragma unroll
        for (int ks = 0; ks < 2; ++ks) {
            const int off = j * WPITCH + ks * 32 + g * 8;   // 16B-aligned
            Bh[nt][ks] = *(const half8*)(Wh + off);
            Bl[nt][ks] = *(const half8*)(Wl + off);
        }
    }

    const long e_base = (long)blockIdx.x * 256 + (long)wv * 64;

    float4v acc[4][3];
    #pragma unroll
    for (int mt = 0; mt < 4; ++mt)
        #pragma unroll
        for (int nt = 0; nt < 3; ++nt)
            #pragma unroll
            for (int i = 0; i < 4; ++i) acc[mt][nt][i] = 0.0f;

    // ---- main loop: 2 K-steps x 4 M-tiles; A from global, split, 12 MFMA ea.
    #pragma unroll
    for (int ks = 0; ks < 2; ++ks) {
        #pragma unroll
        for (int mt = 0; mt < 4; ++mt) {
            long e = e_base + mt * 16 + n15;
            if (e > (long)E_TOT - 1) e = (long)E_TOT - 1;   // clamp (stores guarded)
            const float* row = nbr_fea + e * F_DIM;
            const int k0 = ks * 32 + g * 8;
            half8 ah, al;
            #pragma unroll
            for (int i = 0; i < 8; ++i) {
                const int k = k0 + i;                       // ks=0: always <41
                const float v = (k < F_DIM) ? row[k] : 0.0f;
                const _Float16 vh = (_Float16)v;
                ah[i] = vh;
                al[i] = (_Float16)(v - (float)vh);
            }
            #pragma unroll
            for (int nt = 0; nt < 3; ++nt) {
                acc[mt][nt] = __builtin_amdgcn_mfma_f32_16x16x32_f16(ah, Bh[nt][ks], acc[mt][nt], 0, 0, 0);
                acc[mt][nt] = __builtin_amdgcn_mfma_f32_16x16x32_f16(ah, Bl[nt][ks], acc[mt][nt], 0, 0, 0);
                acc[mt][nt] = __builtin_amdgcn_mfma_f32_16x16x32_f16(al, Bh[nt][ks], acc[mt][nt], 0, 0, 0);
                acc[mt][nt] = __builtin_amdgcn_mfma_f32_16x16x32_f16(al, Bl[nt][ks], acc[mt][nt], 0, 0, 0);
            }
        }
    }

    // ---- epilogue: h -> softplus -> dot w2 col0 -> reduce over j (lane&15)
    float b1v[3], w2v[3];
    #pragma unroll
    for (int nt = 0; nt < 3; ++nt) {
        const int j = nt * 16 + n15;
        b1v[nt] = (j < F_DIM) ? b1[j] : 0.0f;
        w2v[nt] = (j < F_DIM) ? w2[j * 9] : 0.0f;   // zero weight kills pad lanes
    }
    const float b2v   = b2[0];
    const float scale = 0.28209479177387814f / 12.0f;

    #pragma unroll
    for (int mt = 0; mt < 4; ++mt) {
        float p[4];
        #pragma unroll
        for (int r = 0; r < 4; ++r) {
            float sum = 0.0f;
            #pragma unroll
            for (int nt = 0; nt < 3; ++nt) {
                const float v  = acc[mt][nt][r] + b1v[nt];
                const float sp = fmaxf(v, 0.0f) + __logf(1.0f + __expf(-fabsf(v)));
                sum = fmaf(sp, w2v[nt], sum);
            }
            p[r] = sum;
        }
        // butterfly over the 16 j-lanes (C layout: col=lane&15, row=g*4+r)
        #pragma unroll
        for (int m = 1; m < 16; m <<= 1) {
            #pragma unroll
            for (int r = 0; r < 4; ++r) p[r] += __shfl_xor(p[r], m, 64);
        }
        if (n15 == 0) {
            #pragma unroll
            for (int r = 0; r < 4; ++r) {
                const long e = e_base + mt * 16 + g * 4 + r;
                if (e < (long)E_TOT) s_out[e] = (p[r] + b2v) * scale;
            }
        }
    }
}

// ---------------------------------------------------------------------------
// Kernel B1: afT = atom_fea @ (tp_w / 8).  Stage 64 rows coalesced into LDS,
// then wave-uniform ds_read_b128 broadcast reads vs per-lane Tc[64] in VGPRs.
// (Unchanged — its counters surface next round once A drops.)
// ---------------------------------------------------------------------------
__global__ __launch_bounds__(256) void atom_transform_kernel(
    const float* __restrict__ atom_fea,  // [N, C]
    const float* __restrict__ tp_w,      // [C, C]
    float* __restrict__ afT)             // [N, C]
{
    __shared__ float sA[64 * C_DIM];     // 16 KB: 64 atom rows

    const int tid = threadIdx.x;
    const int c   = tid & 63;
    const int wv  = tid >> 6;

    float Tc[64];
    #pragma unroll
    for (int k = 0; k < 64; ++k) Tc[k] = tp_w[k * 64 + c] * 0.125f;  // coalesced

    const long row0 = (long)blockIdx.x * 64;
    long nrem = (long)N_ROWS - row0;
    const int nrow = nrem < 64 ? (int)nrem : 64;

    {
        const float4* g4 = (const float4*)(atom_fea + row0 * C_DIM);
        float4* l4 = (float4*)sA;
        const int tot4 = nrow * 16;
        for (int i = tid; i < tot4; i += 256) l4[i] = g4[i];
    }
    __syncthreads();

    const int r0 = wv * 16;
    for (int i = 0; i < 16; ++i) {
        int rl = r0 + i;                              // wave-uniform
        if (rl >= nrow) break;
        const float4* ar = (const float4*)(sA + rl * C_DIM);   // uniform -> ds broadcast
        float o = 0.0f;
        #pragma unroll
        for (int k4 = 0; k4 < 16; ++k4) {
            float4 a = ar[k4];                        // ds_read_b128, broadcast
            o = fmaf(a.x, Tc[4 * k4 + 0], o);
            o = fmaf(a.y, Tc[4 * k4 + 1], o);
            o = fmaf(a.z, Tc[4 * k4 + 2], o);
            o = fmaf(a.w, Tc[4 * k4 + 3], o);
        }
        afT[(row0 + rl) * C_DIM + c] = o;             // coalesced
    }
}

// ---------------------------------------------------------------------------
// Kernel B2: out[r][:] = sum_j s_rj * afT[idx_rj][:].  Pure gather + 12 FMA,
// float4 per lane, 4 rows in flight per wave, no LDS.  (Unchanged.)
// ---------------------------------------------------------------------------
__global__ __launch_bounds__(256) void gather_kernel(
    const float* __restrict__ afT,       // [N, C]
    const int*   __restrict__ nbr_idx,   // [N, M]
    const float* __restrict__ s,         // [E]
    float* __restrict__ out)             // [N, C]
{
    const int tid  = threadIdx.x;
    const int lane = tid & 63;
    const int wv   = tid >> 6;
    const int q    = lane >> 4;          // row-in-chunk 0..3
    const int c4   = (lane & 15) * 4;    // channel offset

    const int row0 = blockIdx.x * 32 + wv * 8;   // 8 rows per wave (N = 3125*32)

    #pragma unroll
    for (int ch = 0; ch < 2; ++ch) {
        int r = row0 + ch * 4 + q;
        const int*   ir = nbr_idx + r * M_NBR;
        const float* sr = s       + r * M_NBR;
        float4 acc = make_float4(0.f, 0.f, 0.f, 0.f);
        #pragma unroll
        for (int j = 0; j < M_NBR; ++j) {
            int   idx = ir[j];
            float sv  = sr[j];
            const float4 a = *(const float4*)(afT + (long)idx * C_DIM + c4);
            acc.x = fmaf(sv, a.x, acc.x);
            acc.y = fmaf(sv, a.y, acc.y);
            acc.z = fmaf(sv, a.z, acc.z);
            acc.w = fmaf(sv, a.w, acc.w);
        }
        *(float4*)(out + (long)r * C_DIM + c4) = acc;   // coalesced
    }
}

// ---------------------------------------------------------------------------
// Fallback (ws too small for afT): fused gather + LDS-epilogue transform.
// ---------------------------------------------------------------------------
__global__ __launch_bounds__(256) void gather_transform_kernel(
    const float* __restrict__ atom_fea,
    const int*   __restrict__ nbr_idx,
    const float* __restrict__ s,
    const float* __restrict__ tp_w,
    float* __restrict__ out)
{
    __shared__ float accL[64 * C_DIM];
    const int tid = threadIdx.x;
    const int c  = tid & 63;
    const int rq = tid >> 6;

    float Tc[64];
    #pragma unroll
    for (int k = 0; k < 64; ++k) Tc[k] = tp_w[k * 64 + c] * 0.125f;

    const int row0 = blockIdx.x * 64;
    for (int i = 0; i < 16; ++i) {
        int r = row0 + rq * 16 + i;
        float a = 0.0f;
        if (r < N_ROWS) {
            const int*   ir = nbr_idx + (long)r * M_NBR;
            const float* sr = s       + (long)r * M_NBR;
            #pragma unroll
            for (int j = 0; j < M_NBR; ++j)
                a = fmaf(sr[j], atom_fea[(long)ir[j] * C_DIM + c], a);
        }
        accL[(rq * 16 + i) * C_DIM + c] = a;
    }
    __syncthreads();
    for (int i = 0; i < 16; ++i) {
        int rl = rq * 16 + i;
        int r  = row0 + rl;
        if (r >= N_ROWS) continue;
        const float* ar = accL + rl * C_DIM;
        float o = 0.0f;
        #pragma unroll
        for (int k = 0; k < 64; ++k) o = fmaf(ar[k], Tc[k], o);
        out[(long)r * C_DIM + c] = o;
    }
}

extern "C" void kernel_launch(void* const* d_in, const int* in_sizes, int n_in,
                              void* d_out, int out_size, void* d_ws, size_t ws_size,
                              hipStream_t stream) {
    const float* atom_fea = (const float*)d_in[0];
    const float* nbr_fea  = (const float*)d_in[1];
    const int*   nbr_idx  = (const int*)  d_in[2];
    // d_in[3] = pos : dead (only the constant l=0 SH channel couples)
    const float* w1   = (const float*)d_in[4];
    const float* b1   = (const float*)d_in[5];
    const float* w2   = (const float*)d_in[6];
    const float* b2   = (const float*)d_in[7];
    const float* tp_w = (const float*)d_in[8];

    float* s   = (float*)d_ws;                       // 4.8 MB
    float* out = (float*)d_out;

    const int blocksA = (E_TOT + 255) / 256;         // 4688
    edge_mlp_mfma_kernel<<<blocksA, 256, 0, stream>>>(nbr_fea, w1, b1, w2, b2, s);

    const size_t sBytes   = (size_t)E_TOT * sizeof(float);          // 4,800,000 (16B-mult)
    const size_t afTBytes = (size_t)N_ROWS * C_DIM * sizeof(float); // 25.6 MB

    if (ws_size >= sBytes + afTBytes) {
        float* afT = (float*)((char*)d_ws + sBytes);
        const int blocksT = (N_ROWS + 63) / 64;
        atom_transform_kernel<<<blocksT, 256, 0, stream>>>(atom_fea, tp_w, afT);
        const int blocksG = N_ROWS / 32;             // 3125, exact
        gather_kernel<<<blocksG, 256, 0, stream>>>(afT, nbr_idx, s, out);
    } else {
        const int blocksB = (N_ROWS + 63) / 64;
        gather_transform_kernel<<<blocksB, 256, 0, stream>>>(atom_fea, nbr_idx, s, tp_w, out);
    }
}

// Round 5
// 389.284 us; speedup vs baseline: 1.1185x; 1.0436x over previous
//
#include <hip/hip_runtime.h>

#define N_ROWS 100000
#define M_NBR  12
#define C_DIM  64
#define F_DIM  41
#define E_TOT  (N_ROWS * M_NBR)

typedef _Float16 half8 __attribute__((ext_vector_type(8)));
typedef float float4v __attribute__((ext_vector_type(4)));

#define EPITCH 68   // dwords per staged LDS row: 272B (16B-aligned, 68%32=4 -> <=4-way banks)

// fp16 Dekker split: v = hi + lo exactly to ~2^-22 relative
__device__ __forceinline__ void split8(const float (&v)[8], half8& hi, half8& lo) {
    #pragma unroll
    for (int i = 0; i < 8; ++i) {
        const _Float16 h = (_Float16)v[i];
        hi[i] = h;
        lo[i] = (_Float16)(v[i] - (float)h);
    }
}

// ---------------------------------------------------------------------------
// Kernel A v2 (MFMA, coalesced): round 4's A-loads were uncoalesced scalar
// dwords at stride 164B (8 per lane per fragment) -> ~116us. Now: float4
// coalesced global -> LDS (pitch 68, zero-padded cols 41..63) -> ds_read_b128
// fragments. 128 edges/block (E = 9375*128 exact: no tail checks anywhere).
// fp16 Dekker 3-term (al*bl ~2^-22: dropped). Fragment/epilogue layout is
// bit-identical to round 4 (end-to-end validated, absmax 2^-10).
// ---------------------------------------------------------------------------
__global__ __launch_bounds__(256) void edge_mlp_mfma_kernel(
    const float* __restrict__ nbr_fea,   // [E, F]
    const float* __restrict__ w1,        // [F, F]
    const float* __restrict__ b1,        // [F]
    const float* __restrict__ w2,        // [F, 9]
    const float* __restrict__ b2,        // [9]
    float* __restrict__ s_out)           // [E]
{
    __shared__ float lx[128 * EPITCH];   // 34816 B -> 4 blocks/CU

    const int tid  = threadIdx.x;
    const int lane = tid & 63;
    const int wv   = tid >> 6;
    const int n15  = lane & 15;
    const int g    = lane >> 4;
    const long base = (long)blockIdx.x * 128;

    // ---- stage 128 rows coalesced: 5248 floats = 1312 float4 (base 16B-aligned:
    // 128*41*4 = 20992 = 1312*16). Scatter 4 scalars into pitch-68 rows.
    {
        const float4* g4 = (const float4*)(nbr_fea + base * F_DIM);
        for (int i = tid; i < 1312; i += 256) {
            const float4 v = g4[i];
            const int f = 4 * i;
            int r = f / F_DIM;
            int c = f - r * F_DIM;
            const float vv[4] = {v.x, v.y, v.z, v.w};
            #pragma unroll
            for (int t = 0; t < 4; ++t) {
                lx[r * EPITCH + c] = vv[t];
                if (++c == F_DIM) { c = 0; ++r; }
            }
        }
        // zero-pad cols 41..63 (fragment reads touch k up to 63)
        for (int i = tid; i < 128 * 23; i += 256) {
            const int r = i / 23;
            const int c = F_DIM + (i - r * 23);
            lx[r * EPITCH + c] = 0.0f;
        }
    }

    // ---- B fragments from global w1 (6.7KB, L2-hot after first touch);
    // issued before the barrier so they overlap the LDS staging.
    half8 Bh[3][2], Bl[3][2];            // [ntile][kstep]
    #pragma unroll
    for (int nt = 0; nt < 3; ++nt) {
        const int j = nt * 16 + n15;
        #pragma unroll
        for (int ks = 0; ks < 2; ++ks) {
            float v[8];
            #pragma unroll
            for (int i = 0; i < 8; ++i) {
                const int k = ks * 32 + g * 8 + i;
                v[i] = (j < F_DIM && k < F_DIM) ? w1[k * F_DIM + j] : 0.0f;
            }
            split8(v, Bh[nt][ks], Bl[nt][ks]);
        }
    }

    __syncthreads();

    float4v acc[2][3];
    #pragma unroll
    for (int mt = 0; mt < 2; ++mt)
        #pragma unroll
        for (int nt = 0; nt < 3; ++nt)
            #pragma unroll
            for (int i = 0; i < 4; ++i) acc[mt][nt][i] = 0.0f;

    // ---- main: A-frags via 2x ds_read_b128, 3-term Dekker MFMA
    #pragma unroll
    for (int mt = 0; mt < 2; ++mt) {
        const int row = wv * 32 + mt * 16 + n15;
        #pragma unroll
        for (int ks = 0; ks < 2; ++ks) {
            const float* src = lx + row * EPITCH + ks * 32 + g * 8;  // 16B-aligned
            float av[8];
            *(float4*)(av)     = *(const float4*)(src);
            *(float4*)(av + 4) = *(const float4*)(src + 4);
            half8 ah, al;
            split8(av, ah, al);
            #pragma unroll
            for (int nt = 0; nt < 3; ++nt) {
                acc[mt][nt] = __builtin_amdgcn_mfma_f32_16x16x32_f16(ah, Bh[nt][ks], acc[mt][nt], 0, 0, 0);
                acc[mt][nt] = __builtin_amdgcn_mfma_f32_16x16x32_f16(al, Bh[nt][ks], acc[mt][nt], 0, 0, 0);
                acc[mt][nt] = __builtin_amdgcn_mfma_f32_16x16x32_f16(ah, Bl[nt][ks], acc[mt][nt], 0, 0, 0);
            }
        }
    }

    // ---- epilogue (validated round 4): softplus -> w2-dot -> 16-lane butterfly
    float b1v[3], w2v[3];
    #pragma unroll
    for (int nt = 0; nt < 3; ++nt) {
        const int j = nt * 16 + n15;
        b1v[nt] = (j < F_DIM) ? b1[j] : 0.0f;
        w2v[nt] = (j < F_DIM) ? w2[j * 9] : 0.0f;
    }
    const float b2v   = b2[0];
    const float scale = 0.28209479177387814f / 12.0f;

    #pragma unroll
    for (int mt = 0; mt < 2; ++mt) {
        float p[4];
        #pragma unroll
        for (int r = 0; r < 4; ++r) {
            float sum = 0.0f;
            #pragma unroll
            for (int nt = 0; nt < 3; ++nt) {
                const float v  = acc[mt][nt][r] + b1v[nt];
                const float sp = fmaxf(v, 0.0f) + __logf(1.0f + __expf(-fabsf(v)));
                sum = fmaf(sp, w2v[nt], sum);
            }
            p[r] = sum;
        }
        #pragma unroll
        for (int m = 1; m < 16; m <<= 1) {
            #pragma unroll
            for (int r = 0; r < 4; ++r) p[r] += __shfl_xor(p[r], m, 64);
        }
        if (n15 == 0) {
            #pragma unroll
            for (int r = 0; r < 4; ++r) {
                const long e = base + wv * 32 + mt * 16 + g * 4 + r;
                s_out[e] = (p[r] + b2v) * scale;
            }
        }
    }
}

// ---------------------------------------------------------------------------
// Kernel B1 v2 (MFMA): afT = atom_fea @ (tp_w/8). The VALU version was
// DS-pipe bound (1.6M broadcast ds_read_b128 chip-wide ~= 31us). Same staged
// GEMM template as Kernel A: 128 rows/block, K=64 exactly (no padding),
// fp16 Dekker 3-term. Traffic floor 51MB ~= 8us.
// ---------------------------------------------------------------------------
__global__ __launch_bounds__(256) void atom_transform_mfma_kernel(
    const float* __restrict__ atom_fea,  // [N, C]
    const float* __restrict__ tp_w,      // [C, C]
    float* __restrict__ afT)             // [N, C]
{
    __shared__ float lx[128 * EPITCH];   // 34816 B

    const int tid  = threadIdx.x;
    const int lane = tid & 63;
    const int wv   = tid >> 6;
    const int n15  = lane & 15;
    const int g    = lane >> 4;
    const long row0 = (long)blockIdx.x * 128;
    const int nrow = (N_ROWS - row0) < 128 ? (int)(N_ROWS - row0) : 128;

    // stage 128 rows x 16 float4 (rows 256B -> always 16B-aligned); zero-fill tail
    {
        const float4* g4 = (const float4*)(atom_fea + row0 * C_DIM);
        for (int i = tid; i < 128 * 16; i += 256) {
            const int r  = i >> 4;
            const int c4 = i & 15;
            const float4 v = (r < nrow) ? g4[r * 16 + c4] : make_float4(0.f, 0.f, 0.f, 0.f);
            *(float4*)(lx + r * EPITCH + c4 * 4) = v;
        }
    }
    __syncthreads();

    float4v acc[2][4];
    #pragma unroll
    for (int mt = 0; mt < 2; ++mt)
        #pragma unroll
        for (int nt = 0; nt < 4; ++nt)
            #pragma unroll
            for (int i = 0; i < 4; ++i) acc[mt][nt][i] = 0.0f;

    #pragma unroll
    for (int ks = 0; ks < 2; ++ks) {
        // T fragments for this K-step (global, L2-hot; 32 VGPR live at a time)
        half8 Th[4], Tl[4];
        #pragma unroll
        for (int nt = 0; nt < 4; ++nt) {
            const int j = nt * 16 + n15;
            float v[8];
            #pragma unroll
            for (int i = 0; i < 8; ++i) {
                const int k = ks * 32 + g * 8 + i;
                v[i] = tp_w[k * C_DIM + j] * 0.125f;
            }
            split8(v, Th[nt], Tl[nt]);
        }
        #pragma unroll
        for (int mt = 0; mt < 2; ++mt) {
            const int row = wv * 32 + mt * 16 + n15;
            const float* src = lx + row * EPITCH + ks * 32 + g * 8;
            float av[8];
            *(float4*)(av)     = *(const float4*)(src);
            *(float4*)(av + 4) = *(const float4*)(src + 4);
            half8 ah, al;
            split8(av, ah, al);
            #pragma unroll
            for (int nt = 0; nt < 4; ++nt) {
                acc[mt][nt] = __builtin_amdgcn_mfma_f32_16x16x32_f16(ah, Th[nt], acc[mt][nt], 0, 0, 0);
                acc[mt][nt] = __builtin_amdgcn_mfma_f32_16x16x32_f16(al, Th[nt], acc[mt][nt], 0, 0, 0);
                acc[mt][nt] = __builtin_amdgcn_mfma_f32_16x16x32_f16(ah, Tl[nt], acc[mt][nt], 0, 0, 0);
            }
        }
    }

    // store: C row = g*4+r within tile, col = nt*16+n15 (coalesced in n15)
    #pragma unroll
    for (int mt = 0; mt < 2; ++mt) {
        #pragma unroll
        for (int r = 0; r < 4; ++r) {
            const long row = row0 + wv * 32 + mt * 16 + g * 4 + r;
            if (row < N_ROWS) {
                #pragma unroll
                for (int nt = 0; nt < 4; ++nt)
                    afT[row * C_DIM + nt * 16 + n15] = acc[mt][nt][r];
            }
        }
    }
}

// ---------------------------------------------------------------------------
// Kernel B2: out[r][:] = sum_j s_rj * afT[idx_rj][:].  (Unchanged — random
// 256B gather, ~342MB effective; next-round target if B-side stays big.)
// ---------------------------------------------------------------------------
__global__ __launch_bounds__(256) void gather_kernel(
    const float* __restrict__ afT,       // [N, C]
    const int*   __restrict__ nbr_idx,   // [N, M]
    const float* __restrict__ s,         // [E]
    float* __restrict__ out)             // [N, C]
{
    const int tid  = threadIdx.x;
    const int lane = tid & 63;
    const int wv   = tid >> 6;
    const int q    = lane >> 4;          // row-in-chunk 0..3
    const int c4   = (lane & 15) * 4;    // channel offset

    const int row0 = blockIdx.x * 32 + wv * 8;   // 8 rows per wave (N = 3125*32)

    #pragma unroll
    for (int ch = 0; ch < 2; ++ch) {
        int r = row0 + ch * 4 + q;
        const int*   ir = nbr_idx + r * M_NBR;
        const float* sr = s       + r * M_NBR;
        float4 acc = make_float4(0.f, 0.f, 0.f, 0.f);
        #pragma unroll
        for (int j = 0; j < M_NBR; ++j) {
            int   idx = ir[j];
            float sv  = sr[j];
            const float4 a = *(const float4*)(afT + (long)idx * C_DIM + c4);
            acc.x = fmaf(sv, a.x, acc.x);
            acc.y = fmaf(sv, a.y, acc.y);
            acc.z = fmaf(sv, a.z, acc.z);
            acc.w = fmaf(sv, a.w, acc.w);
        }
        *(float4*)(out + (long)r * C_DIM + c4) = acc;   // coalesced
    }
}

// ---------------------------------------------------------------------------
// Fallback (ws too small for afT): fused gather + LDS-epilogue transform.
// ---------------------------------------------------------------------------
__global__ __launch_bounds__(256) void gather_transform_kernel(
    const float* __restrict__ atom_fea,
    const int*   __restrict__ nbr_idx,
    const float* __restrict__ s,
    const float* __restrict__ tp_w,
    float* __restrict__ out)
{
    __shared__ float accL[64 * C_DIM];
    const int tid = threadIdx.x;
    const int c  = tid & 63;
    const int rq = tid >> 6;

    float Tc[64];
    #pragma unroll
    for (int k = 0; k < 64; ++k) Tc[k] = tp_w[k * 64 + c] * 0.125f;

    const int row0 = blockIdx.x * 64;
    for (int i = 0; i < 16; ++i) {
        int r = row0 + rq * 16 + i;
        float a = 0.0f;
        if (r < N_ROWS) {
            const int*   ir = nbr_idx + (long)r * M_NBR;
            const float* sr = s       + (long)r * M_NBR;
            #pragma unroll
            for (int j = 0; j < M_NBR; ++j)
                a = fmaf(sr[j], atom_fea[(long)ir[j] * C_DIM + c], a);
        }
        accL[(rq * 16 + i) * C_DIM + c] = a;
    }
    __syncthreads();
    for (int i = 0; i < 16; ++i) {
        int rl = rq * 16 + i;
        int r  = row0 + rl;
        if (r >= N_ROWS) continue;
        const float* ar = accL + rl * C_DIM;
        float o = 0.0f;
        #pragma unroll
        for (int k = 0; k < 64; ++k) o = fmaf(ar[k], Tc[k], o);
        out[(long)r * C_DIM + c] = o;
    }
}

extern "C" void kernel_launch(void* const* d_in, const int* in_sizes, int n_in,
                              void* d_out, int out_size, void* d_ws, size_t ws_size,
                              hipStream_t stream) {
    const float* atom_fea = (const float*)d_in[0];
    const float* nbr_fea  = (const float*)d_in[1];
    const int*   nbr_idx  = (const int*)  d_in[2];
    // d_in[3] = pos : dead (only the constant l=0 SH channel couples)
    const float* w1   = (const float*)d_in[4];
    const float* b1   = (const float*)d_in[5];
    const float* w2   = (const float*)d_in[6];
    const float* b2   = (const float*)d_in[7];
    const float* tp_w = (const float*)d_in[8];

    float* s   = (float*)d_ws;                       // 4.8 MB
    float* out = (float*)d_out;

    const int blocksA = E_TOT / 128;                 // 9375, exact
    edge_mlp_mfma_kernel<<<blocksA, 256, 0, stream>>>(nbr_fea, w1, b1, w2, b2, s);

    const size_t sBytes   = (size_t)E_TOT * sizeof(float);          // 4,800,000 (16B-mult)
    const size_t afTBytes = (size_t)N_ROWS * C_DIM * sizeof(float); // 25.6 MB

    if (ws_size >= sBytes + afTBytes) {
        float* afT = (float*)((char*)d_ws + sBytes);
        const int blocksT = (N_ROWS + 127) / 128;    // 782
        atom_transform_mfma_kernel<<<blocksT, 256, 0, stream>>>(atom_fea, tp_w, afT);
        const int blocksG = N_ROWS / 32;             // 3125, exact
        gather_kernel<<<blocksG, 256, 0, stream>>>(afT, nbr_idx, s, out);
    } else {
        const int blocksB = (N_ROWS + 63) / 64;
        gather_transform_kernel<<<blocksB, 256, 0, stream>>>(atom_fea, nbr_idx, s, tp_w, out);
    }
}

// Round 6
// 354.382 us; speedup vs baseline: 1.2287x; 1.0985x over previous
//
#include <hip/hip_runtime.h>

#define N_ROWS 100000
#define M_NBR  12
#define C_DIM  64
#define F_DIM  41
#define E_TOT  (N_ROWS * M_NBR)

typedef _Float16 half8 __attribute__((ext_vector_type(8)));
typedef _Float16 half4v __attribute__((ext_vector_type(4)));
typedef float float4v __attribute__((ext_vector_type(4)));

#define EPITCH   68   // fp32 LDS pitch (B1): 272B, 16B-aligned
#define EPITCH_H 72   // fp16 LDS pitch (edge): 144B, 16B-aligned, 2-way banks

// fp16 Dekker split (kept for B1 only)
__device__ __forceinline__ void split8(const float (&v)[8], half8& hi, half8& lo) {
    #pragma unroll
    for (int i = 0; i < 8; ++i) {
        const _Float16 h = (_Float16)v[i];
        hi[i] = h;
        lo[i] = (_Float16)(v[i] - (float)h);
    }
}

// ---------------------------------------------------------------------------
// Prep: pack W1^T (+ b1 as the k=41 row) into per-lane fp16 B-fragments,
// ONCE for the whole launch. Round 5's edge kernel rebuilt these per block:
// 48 uncoalesced w1 gathers + 144 cvt VALU x 9375 blocks. Layout:
// bpack[((nt*2+ks)*64 + lane)*8 .. +7] = lane's half8 for that (nt,ks).
// ---------------------------------------------------------------------------
__global__ __launch_bounds__(64) void prep_edge_B(
    const float* __restrict__ w1,   // [F, F]
    const float* __restrict__ b1,   // [F]
    _Float16* __restrict__ bpack)   // [3*2*64*8]
{
    const int lane = threadIdx.x;
    const int n15 = lane & 15, g = lane >> 4;
    #pragma unroll
    for (int nt = 0; nt < 3; ++nt) {
        const int j = nt * 16 + n15;
        #pragma unroll
        for (int ks = 0; ks < 2; ++ks) {
            half8 v;
            #pragma unroll
            for (int i = 0; i < 8; ++i) {
                const int k = ks * 32 + g * 8 + i;
                float f = 0.0f;
                if (j < F_DIM) {
                    if (k < F_DIM)       f = w1[k * F_DIM + j];
                    else if (k == F_DIM) f = b1[j];       // bias folded as row 41
                }
                v[i] = (_Float16)f;
            }
            *(half8*)(bpack + ((nt * 2 + ks) * 64 + lane) * 8) = v;
        }
    }
}

// ---------------------------------------------------------------------------
// Kernel A v3 (MFMA, VALU diet): round 5 counters showed VALU-bound
// (VALUBusy 69%, MfmaUtil 7.7, HBM 11%). Cuts: single-term fp16 (error
// ~1e-4 at out, vs 0.00098 fp32 baseline that passed), B-frags preloaded
// from bpack (6 coalesced 16B loads), b1 folded into k=41 (A col 41 = 1),
// A staged as fp16 in LDS (cvt during staging; main loop = 1 ds_read_b128
// + 3 MFMA per step). 12 MFMA/thread total.
// ---------------------------------------------------------------------------
__global__ __launch_bounds__(256) void edge_mlp_mfma_kernel(
    const float* __restrict__ nbr_fea,   // [E, F]
    const _Float16* __restrict__ bpack,  // packed B fragments (+bias row)
    const float* __restrict__ w2,        // [F, 9]
    const float* __restrict__ b2,        // [9]
    float* __restrict__ s_out)           // [E]
{
    __shared__ _Float16 lx[128 * EPITCH_H];   // 18432 B

    const int tid  = threadIdx.x;
    const int lane = tid & 63;
    const int wv   = tid >> 6;
    const int n15  = lane & 15;
    const int g    = lane >> 4;
    const long base = (long)blockIdx.x * 128;

    // ---- stage 128 rows coalesced, converting to fp16 on the fly
    {
        const float4* g4 = (const float4*)(nbr_fea + base * F_DIM);  // 20992B/blk: 16B-aligned
        for (int i = tid; i < 1312; i += 256) {
            const float4 v = g4[i];
            const int f = 4 * i;
            int r = f / F_DIM;
            int c = f - r * F_DIM;
            const float vv[4] = {v.x, v.y, v.z, v.w};
            #pragma unroll
            for (int t = 0; t < 4; ++t) {
                lx[r * EPITCH_H + c] = (_Float16)vv[t];
                if (++c == F_DIM) { c = 0; ++r; }
            }
        }
        // cols 41..63: col 41 = 1.0 (bias), rest 0
        for (int i = tid; i < 128 * 23; i += 256) {
            const int r = i / 23;
            const int c = F_DIM + (i - r * 23);
            lx[r * EPITCH_H + c] = (c == F_DIM) ? (_Float16)1.0f : (_Float16)0.0f;
        }
    }

    // ---- B fragments: 6 coalesced 16B loads (issued pre-barrier, overlap staging)
    half8 Bh[3][2];
    #pragma unroll
    for (int nt = 0; nt < 3; ++nt)
        #pragma unroll
        for (int ks = 0; ks < 2; ++ks)
            Bh[nt][ks] = *(const half8*)(bpack + ((nt * 2 + ks) * 64 + lane) * 8);

    __syncthreads();

    float4v acc[2][3];
    #pragma unroll
    for (int mt = 0; mt < 2; ++mt)
        #pragma unroll
        for (int nt = 0; nt < 3; ++nt)
            #pragma unroll
            for (int i = 0; i < 4; ++i) acc[mt][nt][i] = 0.0f;

    // ---- main: 1 ds_read_b128 + 3 MFMA per (mt,ks)
    #pragma unroll
    for (int mt = 0; mt < 2; ++mt) {
        const int row = wv * 32 + mt * 16 + n15;
        #pragma unroll
        for (int ks = 0; ks < 2; ++ks) {
            const half8 a = *(const half8*)(lx + row * EPITCH_H + ks * 32 + g * 8);  // 16B-aligned
            #pragma unroll
            for (int nt = 0; nt < 3; ++nt)
                acc[mt][nt] = __builtin_amdgcn_mfma_f32_16x16x32_f16(a, Bh[nt][ks], acc[mt][nt], 0, 0, 0);
        }
    }

    // ---- epilogue: softplus (h already includes b1) -> w2-dot -> butterfly
    float w2v[3];
    #pragma unroll
    for (int nt = 0; nt < 3; ++nt) {
        const int j = nt * 16 + n15;
        w2v[nt] = (j < F_DIM) ? w2[j * 9] : 0.0f;   // zero kills pad lanes
    }
    const float b2v   = b2[0];
    const float scale = 0.28209479177387814f / 12.0f;

    #pragma unroll
    for (int mt = 0; mt < 2; ++mt) {
        float p[4];
        #pragma unroll
        for (int r = 0; r < 4; ++r) {
            float sum = 0.0f;
            #pragma unroll
            for (int nt = 0; nt < 3; ++nt) {
                const float v  = acc[mt][nt][r];
                const float sp = fmaxf(v, 0.0f) + __logf(1.0f + __expf(-fabsf(v)));
                sum = fmaf(sp, w2v[nt], sum);
            }
            p[r] = sum;
        }
        #pragma unroll
        for (int m = 1; m < 16; m <<= 1) {
            #pragma unroll
            for (int r = 0; r < 4; ++r) p[r] += __shfl_xor(p[r], m, 64);
        }
        if (n15 == 0) {
            #pragma unroll
            for (int r = 0; r < 4; ++r) {
                const long e = base + wv * 32 + mt * 16 + g * 4 + r;
                s_out[e] = (p[r] + b2v) * scale;
            }
        }
    }
}

// ---------------------------------------------------------------------------
// Kernel B1 v3 (MFMA): afT = atom_fea @ (tp_w/8), OUTPUT IN FP16 (halves
// B2's gather traffic; quant err ~3e-5 at out). Internals unchanged from
// validated round-5 version (3-term Dekker).
// ---------------------------------------------------------------------------
__global__ __launch_bounds__(256) void atom_transform_mfma_kernel(
    const float* __restrict__ atom_fea,  // [N, C]
    const float* __restrict__ tp_w,      // [C, C]
    _Float16* __restrict__ afT)          // [N, C] fp16
{
    __shared__ float lx[128 * EPITCH];   // 34816 B

    const int tid  = threadIdx.x;
    const int lane = tid & 63;
    const int wv   = tid >> 6;
    const int n15  = lane & 15;
    const int g    = lane >> 4;
    const long row0 = (long)blockIdx.x * 128;
    const int nrow = (N_ROWS - row0) < 128 ? (int)(N_ROWS - row0) : 128;

    {
        const float4* g4 = (const float4*)(atom_fea + row0 * C_DIM);
        for (int i = tid; i < 128 * 16; i += 256) {
            const int r  = i >> 4;
            const int c4 = i & 15;
            const float4 v = (r < nrow) ? g4[r * 16 + c4] : make_float4(0.f, 0.f, 0.f, 0.f);
            *(float4*)(lx + r * EPITCH + c4 * 4) = v;
        }
    }
    __syncthreads();

    float4v acc[2][4];
    #pragma unroll
    for (int mt = 0; mt < 2; ++mt)
        #pragma unroll
        for (int nt = 0; nt < 4; ++nt)
            #pragma unroll
            for (int i = 0; i < 4; ++i) acc[mt][nt][i] = 0.0f;

    #pragma unroll
    for (int ks = 0; ks < 2; ++ks) {
        half8 Th[4], Tl[4];
        #pragma unroll
        for (int nt = 0; nt < 4; ++nt) {
            const int j = nt * 16 + n15;
            float v[8];
            #pragma unroll
            for (int i = 0; i < 8; ++i) {
                const int k = ks * 32 + g * 8 + i;
                v[i] = tp_w[k * C_DIM + j] * 0.125f;
            }
            split8(v, Th[nt], Tl[nt]);
        }
        #pragma unroll
        for (int mt = 0; mt < 2; ++mt) {
            const int row = wv * 32 + mt * 16 + n15;
            const float* src = lx + row * EPITCH + ks * 32 + g * 8;
            float av[8];
            *(float4*)(av)     = *(const float4*)(src);
            *(float4*)(av + 4) = *(const float4*)(src + 4);
            half8 ah, al;
            split8(av, ah, al);
            #pragma unroll
            for (int nt = 0; nt < 4; ++nt) {
                acc[mt][nt] = __builtin_amdgcn_mfma_f32_16x16x32_f16(ah, Th[nt], acc[mt][nt], 0, 0, 0);
                acc[mt][nt] = __builtin_amdgcn_mfma_f32_16x16x32_f16(al, Th[nt], acc[mt][nt], 0, 0, 0);
                acc[mt][nt] = __builtin_amdgcn_mfma_f32_16x16x32_f16(ah, Tl[nt], acc[mt][nt], 0, 0, 0);
            }
        }
    }

    #pragma unroll
    for (int mt = 0; mt < 2; ++mt) {
        #pragma unroll
        for (int r = 0; r < 4; ++r) {
            const long row = row0 + wv * 32 + mt * 16 + g * 4 + r;
            if (row < N_ROWS) {
                #pragma unroll
                for (int nt = 0; nt < 4; ++nt)
                    afT[row * C_DIM + nt * 16 + n15] = (_Float16)acc[mt][nt][r];
            }
        }
    }
}

// ---------------------------------------------------------------------------
// Kernel B2 v2: out[r][:] = sum_j s_rj * afT16[idx_rj][:].  fp16 gather:
// 8B/lane (128B per gathered row, was 256B) -> gather traffic halved and
// afT (12.8MB) far more L2-resident.
// ---------------------------------------------------------------------------
__global__ __launch_bounds__(256) void gather_kernel(
    const _Float16* __restrict__ afT,    // [N, C] fp16
    const int*   __restrict__ nbr_idx,   // [N, M]
    const float* __restrict__ s,         // [E]
    float* __restrict__ out)             // [N, C]
{
    const int tid  = threadIdx.x;
    const int lane = tid & 63;
    const int wv   = tid >> 6;
    const int q    = lane >> 4;          // row-in-chunk 0..3
    const int c4   = (lane & 15) * 4;    // channel offset

    const int row0 = blockIdx.x * 32 + wv * 8;   // 8 rows per wave (N = 3125*32)

    #pragma unroll
    for (int ch = 0; ch < 2; ++ch) {
        int r = row0 + ch * 4 + q;
        const int*   ir = nbr_idx + r * M_NBR;
        const float* sr = s       + r * M_NBR;
        float4 acc = make_float4(0.f, 0.f, 0.f, 0.f);
        #pragma unroll
        for (int j = 0; j < M_NBR; ++j) {
            int   idx = ir[j];
            float sv  = sr[j];
            const half4v a = *(const half4v*)(afT + (long)idx * C_DIM + c4);  // 8B-aligned
            acc.x = fmaf(sv, (float)a[0], acc.x);
            acc.y = fmaf(sv, (float)a[1], acc.y);
            acc.z = fmaf(sv, (float)a[2], acc.z);
            acc.w = fmaf(sv, (float)a[3], acc.w);
        }
        *(float4*)(out + (long)r * C_DIM + c4) = acc;   // coalesced
    }
}

// ---------------------------------------------------------------------------
// Fallback (ws too small for afT): fused gather + LDS-epilogue transform
// (fp32, reads atom_fea directly; only needs bpack + s in ws).
// ---------------------------------------------------------------------------
__global__ __launch_bounds__(256) void gather_transform_kernel(
    const float* __restrict__ atom_fea,
    const int*   __restrict__ nbr_idx,
    const float* __restrict__ s,
    const float* __restrict__ tp_w,
    float* __restrict__ out)
{
    __shared__ float accL[64 * C_DIM];
    const int tid = threadIdx.x;
    const int c  = tid & 63;
    const int rq = tid >> 6;

    float Tc[64];
    #pragma unroll
    for (int k = 0; k < 64; ++k) Tc[k] = tp_w[k * 64 + c] * 0.125f;

    const int row0 = blockIdx.x * 64;
    for (int i = 0; i < 16; ++i) {
        int r = row0 + rq * 16 + i;
        float a = 0.0f;
        if (r < N_ROWS) {
            const int*   ir = nbr_idx + (long)r * M_NBR;
            const float* sr = s       + (long)r * M_NBR;
            #pragma unroll
            for (int j = 0; j < M_NBR; ++j)
                a = fmaf(sr[j], atom_fea[(long)ir[j] * C_DIM + c], a);
        }
        accL[(rq * 16 + i) * C_DIM + c] = a;
    }
    __syncthreads();
    for (int i = 0; i < 16; ++i) {
        int rl = rq * 16 + i;
        int r  = row0 + rl;
        if (r >= N_ROWS) continue;
        const float* ar = accL + rl * C_DIM;
        float o = 0.0f;
        #pragma unroll
        for (int k = 0; k < 64; ++k) o = fmaf(ar[k], Tc[k], o);
        out[(long)r * C_DIM + c] = o;
    }
}

extern "C" void kernel_launch(void* const* d_in, const int* in_sizes, int n_in,
                              void* d_out, int out_size, void* d_ws, size_t ws_size,
                              hipStream_t stream) {
    const float* atom_fea = (const float*)d_in[0];
    const float* nbr_fea  = (const float*)d_in[1];
    const int*   nbr_idx  = (const int*)  d_in[2];
    // d_in[3] = pos : dead (only the constant l=0 SH channel couples)
    const float* w1   = (const float*)d_in[4];
    const float* b1   = (const float*)d_in[5];
    const float* w2   = (const float*)d_in[6];
    const float* b2   = (const float*)d_in[7];
    const float* tp_w = (const float*)d_in[8];

    // ws layout: [bpack 8KB][s 4.8MB][afT16 12.8MB]
    _Float16* bpack = (_Float16*)d_ws;
    float*    s     = (float*)((char*)d_ws + 8192);
    float*    out   = (float*)d_out;

    const size_t sBytes    = (size_t)E_TOT * sizeof(float);              // 4,800,000
    const size_t afTBytes  = (size_t)N_ROWS * C_DIM * sizeof(_Float16);  // 12.8 MB

    prep_edge_B<<<1, 64, 0, stream>>>(w1, b1, bpack);

    const int blocksA = E_TOT / 128;                 // 9375, exact
    edge_mlp_mfma_kernel<<<blocksA, 256, 0, stream>>>(nbr_fea, bpack, w2, b2, s);

    if (ws_size >= 8192 + sBytes + afTBytes) {
        _Float16* afT = (_Float16*)((char*)d_ws + 8192 + sBytes);
        const int blocksT = (N_ROWS + 127) / 128;    // 782
        atom_transform_mfma_kernel<<<blocksT, 256, 0, stream>>>(atom_fea, tp_w, afT);
        const int blocksG = N_ROWS / 32;             // 3125, exact
        gather_kernel<<<blocksG, 256, 0, stream>>>(afT, nbr_idx, s, out);
    } else {
        const int blocksB = (N_ROWS + 63) / 64;
        gather_transform_kernel<<<blocksB, 256, 0, stream>>>(atom_fea, nbr_idx, s, tp_w, out);
    }
}

// Round 7
// 346.430 us; speedup vs baseline: 1.2569x; 1.0230x over previous
//
#include <hip/hip_runtime.h>

#define N_ROWS 100000
#define M_NBR  12
#define C_DIM  64
#define F_DIM  41
#define E_TOT  (N_ROWS * M_NBR)

typedef _Float16 half8 __attribute__((ext_vector_type(8)));
typedef _Float16 half4v __attribute__((ext_vector_type(4)));
typedef float float4v __attribute__((ext_vector_type(4)));

#define EPITCH   68   // fp32 LDS pitch (B1): 272B, 16B-aligned
#define EPITCH_H 72   // fp16 LDS pitch (edge): 144B, 16B-aligned

// fp16 Dekker split (B1 only)
__device__ __forceinline__ void split8(const float (&v)[8], half8& hi, half8& lo) {
    #pragma unroll
    for (int i = 0; i < 8; ++i) {
        const _Float16 h = (_Float16)v[i];
        hi[i] = h;
        lo[i] = (_Float16)(v[i] - (float)h);
    }
}

// ---------------------------------------------------------------------------
// Prep: pack W1^T (+ b1 as the k=41 row) into per-lane fp16 B-fragments once.
// v2: 6 waves (one per (nt,ks) fragment) instead of 1 wave -> shorter serial
// head before the edge kernel.
// ---------------------------------------------------------------------------
__global__ __launch_bounds__(384) void prep_edge_B(
    const float* __restrict__ w1,   // [F, F]
    const float* __restrict__ b1,   // [F]
    _Float16* __restrict__ bpack)   // [3*2*64*8]
{
    const int tid  = threadIdx.x;
    const int wid  = tid >> 6;           // 0..5
    const int lane = tid & 63;
    const int nt   = wid >> 1;
    const int ks   = wid & 1;
    const int n15  = lane & 15, g = lane >> 4;

    const int j = nt * 16 + n15;
    half8 v;
    #pragma unroll
    for (int i = 0; i < 8; ++i) {
        const int k = ks * 32 + g * 8 + i;
        float f = 0.0f;
        if (j < F_DIM) {
            if (k < F_DIM)       f = w1[k * F_DIM + j];
            else if (k == F_DIM) f = b1[j];       // bias folded as row 41
        }
        v[i] = (_Float16)f;
    }
    *(half8*)(bpack + ((nt * 2 + ks) * 64 + lane) * 8) = v;
}

// ---------------------------------------------------------------------------
// Kernel A v4 (MFMA, zero-arithmetic staging): v3's staging scatter cost
// ~285 VALU/thread (magic-div by 41 & 23, per-element wrap checks, u16
// writes -> R5's 3.6M bank conflicts). Replaced by 3 phases with no
// per-element address math:
//   A) linear coalesced float4 copy g->LDS (packed fp32)
//   B) row-owner (t<128) reads its 41 floats: ds_read_b32 with IMMEDIATE
//      offsets off one base (dword stride 41 odd -> conflict-free)
//   C) cvt to fp16 in regs (RTN, numerically identical to v3), bias@41 +
//      zeros 42..63 baked into 8 static-indexed half8, 8x ds_write_b128
//      at pitch 72 (2-way within-phase banks = free)
// Main loop + epilogue bit-identical to validated v3.
// ---------------------------------------------------------------------------
__global__ __launch_bounds__(256) void edge_mlp_mfma_kernel(
    const float* __restrict__ nbr_fea,   // [E, F]
    const _Float16* __restrict__ bpack,  // packed B fragments (+bias row)
    const float* __restrict__ w2,        // [F, 9]
    const float* __restrict__ b2,        // [9]
    float* __restrict__ s_out)           // [E]
{
    __shared__ float lsf[128 * F_DIM];           // 20992 B; aliased fp16 pitch-72 after
    _Float16* lsh = (_Float16*)lsf;              // fp16 rows use bytes [0, 18432)

    const int tid  = threadIdx.x;
    const int lane = tid & 63;
    const int wv   = tid >> 6;
    const int n15  = lane & 15;
    const int g    = lane >> 4;
    const long base = (long)blockIdx.x * 128;

    // ---- B fragments: 6 coalesced 16B loads (overlap the staging below)
    half8 Bh[3][2];
    #pragma unroll
    for (int nt = 0; nt < 3; ++nt)
        #pragma unroll
        for (int ks = 0; ks < 2; ++ks)
            Bh[nt][ks] = *(const half8*)(bpack + ((nt * 2 + ks) * 64 + lane) * 8);

    // ---- phase A: linear coalesced copy, zero arithmetic
    {
        const float4* g4 = (const float4*)(nbr_fea + base * F_DIM);  // 20992B/blk: 16B-aligned
        float4* l4 = (float4*)lsf;
        for (int i = tid; i < 1312; i += 256) l4[i] = g4[i];
    }
    __syncthreads();

    // ---- phase B: row-owner reads its packed row (imm-offset ds_read_b32)
    float xr[F_DIM];
    const bool owner = tid < 128;
    if (owner) {
        const float* src = lsf + tid * F_DIM;
        #pragma unroll
        for (int k = 0; k < F_DIM; ++k) xr[k] = src[k];
    }
    __syncthreads();   // all packed reads done before fp16 overwrite

    // ---- phase C: cvt + write fp16 row (pitch 72), bias/zeros baked in
    if (owner) {
        half8 hv[8];
        #pragma unroll
        for (int q = 0; q < 8; ++q) {
            #pragma unroll
            for (int i = 0; i < 8; ++i) {
                const int k = q * 8 + i;
                _Float16 h = (_Float16)0.0f;
                if (k < F_DIM)       h = (_Float16)xr[k];   // RTN cast == v3
                else if (k == F_DIM) h = (_Float16)1.0f;    // bias column
                hv[q][i] = h;
            }
        }
        _Float16* dst = lsh + tid * EPITCH_H;
        #pragma unroll
        for (int q = 0; q < 8; ++q)
            *(half8*)(dst + q * 8) = hv[q];
    }
    __syncthreads();

    float4v acc[2][3];
    #pragma unroll
    for (int mt = 0; mt < 2; ++mt)
        #pragma unroll
        for (int nt = 0; nt < 3; ++nt)
            #pragma unroll
            for (int i = 0; i < 4; ++i) acc[mt][nt][i] = 0.0f;

    // ---- main: 1 ds_read_b128 + 3 MFMA per (mt,ks)
    #pragma unroll
    for (int mt = 0; mt < 2; ++mt) {
        const int row = wv * 32 + mt * 16 + n15;
        #pragma unroll
        for (int ks = 0; ks < 2; ++ks) {
            const half8 a = *(const half8*)(lsh + row * EPITCH_H + ks * 32 + g * 8);  // 16B-aligned
            #pragma unroll
            for (int nt = 0; nt < 3; ++nt)
                acc[mt][nt] = __builtin_amdgcn_mfma_f32_16x16x32_f16(a, Bh[nt][ks], acc[mt][nt], 0, 0, 0);
        }
    }

    // ---- epilogue: softplus (h includes b1) -> w2-dot -> butterfly
    float w2v[3];
    #pragma unroll
    for (int nt = 0; nt < 3; ++nt) {
        const int j = nt * 16 + n15;
        w2v[nt] = (j < F_DIM) ? w2[j * 9] : 0.0f;   // zero kills pad lanes
    }
    const float b2v   = b2[0];
    const float scale = 0.28209479177387814f / 12.0f;

    #pragma unroll
    for (int mt = 0; mt < 2; ++mt) {
        float p[4];
        #pragma unroll
        for (int r = 0; r < 4; ++r) {
            float sum = 0.0f;
            #pragma unroll
            for (int nt = 0; nt < 3; ++nt) {
                const float v  = acc[mt][nt][r];
                const float sp = fmaxf(v, 0.0f) + __logf(1.0f + __expf(-fabsf(v)));
                sum = fmaf(sp, w2v[nt], sum);
            }
            p[r] = sum;
        }
        #pragma unroll
        for (int m = 1; m < 16; m <<= 1) {
            #pragma unroll
            for (int r = 0; r < 4; ++r) p[r] += __shfl_xor(p[r], m, 64);
        }
        if (n15 == 0) {
            #pragma unroll
            for (int r = 0; r < 4; ++r) {
                const long e = base + wv * 32 + mt * 16 + g * 4 + r;
                s_out[e] = (p[r] + b2v) * scale;
            }
        }
    }
}

// ---------------------------------------------------------------------------
// Kernel B1 v3 (MFMA): afT = atom_fea @ (tp_w/8), fp16 output. Unchanged.
// ---------------------------------------------------------------------------
__global__ __launch_bounds__(256) void atom_transform_mfma_kernel(
    const float* __restrict__ atom_fea,  // [N, C]
    const float* __restrict__ tp_w,      // [C, C]
    _Float16* __restrict__ afT)          // [N, C] fp16
{
    __shared__ float lx[128 * EPITCH];   // 34816 B

    const int tid  = threadIdx.x;
    const int lane = tid & 63;
    const int wv   = tid >> 6;
    const int n15  = lane & 15;
    const int g    = lane >> 4;
    const long row0 = (long)blockIdx.x * 128;
    const int nrow = (N_ROWS - row0) < 128 ? (int)(N_ROWS - row0) : 128;

    {
        const float4* g4 = (const float4*)(atom_fea + row0 * C_DIM);
        for (int i = tid; i < 128 * 16; i += 256) {
            const int r  = i >> 4;
            const int c4 = i & 15;
            const float4 v = (r < nrow) ? g4[r * 16 + c4] : make_float4(0.f, 0.f, 0.f, 0.f);
            *(float4*)(lx + r * EPITCH + c4 * 4) = v;
        }
    }
    __syncthreads();

    float4v acc[2][4];
    #pragma unroll
    for (int mt = 0; mt < 2; ++mt)
        #pragma unroll
        for (int nt = 0; nt < 4; ++nt)
            #pragma unroll
            for (int i = 0; i < 4; ++i) acc[mt][nt][i] = 0.0f;

    #pragma unroll
    for (int ks = 0; ks < 2; ++ks) {
        half8 Th[4], Tl[4];
        #pragma unroll
        for (int nt = 0; nt < 4; ++nt) {
            const int j = nt * 16 + n15;
            float v[8];
            #pragma unroll
            for (int i = 0; i < 8; ++i) {
                const int k = ks * 32 + g * 8 + i;
                v[i] = tp_w[k * C_DIM + j] * 0.125f;
            }
            split8(v, Th[nt], Tl[nt]);
        }
        #pragma unroll
        for (int mt = 0; mt < 2; ++mt) {
            const int row = wv * 32 + mt * 16 + n15;
            const float* src = lx + row * EPITCH + ks * 32 + g * 8;
            float av[8];
            *(float4*)(av)     = *(const float4*)(src);
            *(float4*)(av + 4) = *(const float4*)(src + 4);
            half8 ah, al;
            split8(av, ah, al);
            #pragma unroll
            for (int nt = 0; nt < 4; ++nt) {
                acc[mt][nt] = __builtin_amdgcn_mfma_f32_16x16x32_f16(ah, Th[nt], acc[mt][nt], 0, 0, 0);
                acc[mt][nt] = __builtin_amdgcn_mfma_f32_16x16x32_f16(al, Th[nt], acc[mt][nt], 0, 0, 0);
                acc[mt][nt] = __builtin_amdgcn_mfma_f32_16x16x32_f16(ah, Tl[nt], acc[mt][nt], 0, 0, 0);
            }
        }
    }

    #pragma unroll
    for (int mt = 0; mt < 2; ++mt) {
        #pragma unroll
        for (int r = 0; r < 4; ++r) {
            const long row = row0 + wv * 32 + mt * 16 + g * 4 + r;
            if (row < N_ROWS) {
                #pragma unroll
                for (int nt = 0; nt < 4; ++nt)
                    afT[row * C_DIM + nt * 16 + n15] = (_Float16)acc[mt][nt][r];
            }
        }
    }
}

// ---------------------------------------------------------------------------
// Kernel B2 v2: out[r][:] = sum_j s_rj * afT16[idx_rj][:]. Unchanged.
// ---------------------------------------------------------------------------
__global__ __launch_bounds__(256) void gather_kernel(
    const _Float16* __restrict__ afT,    // [N, C] fp16
    const int*   __restrict__ nbr_idx,   // [N, M]
    const float* __restrict__ s,         // [E]
    float* __restrict__ out)             // [N, C]
{
    const int tid  = threadIdx.x;
    const int lane = tid & 63;
    const int wv   = tid >> 6;
    const int q    = lane >> 4;          // row-in-chunk 0..3
    const int c4   = (lane & 15) * 4;    // channel offset

    const int row0 = blockIdx.x * 32 + wv * 8;   // 8 rows per wave (N = 3125*32)

    #pragma unroll
    for (int ch = 0; ch < 2; ++ch) {
        int r = row0 + ch * 4 + q;
        const int*   ir = nbr_idx + r * M_NBR;
        const float* sr = s       + r * M_NBR;
        float4 acc = make_float4(0.f, 0.f, 0.f, 0.f);
        #pragma unroll
        for (int j = 0; j < M_NBR; ++j) {
            int   idx = ir[j];
            float sv  = sr[j];
            const half4v a = *(const half4v*)(afT + (long)idx * C_DIM + c4);  // 8B-aligned
            acc.x = fmaf(sv, (float)a[0], acc.x);
            acc.y = fmaf(sv, (float)a[1], acc.y);
            acc.z = fmaf(sv, (float)a[2], acc.z);
            acc.w = fmaf(sv, (float)a[3], acc.w);
        }
        *(float4*)(out + (long)r * C_DIM + c4) = acc;   // coalesced
    }
}

// ---------------------------------------------------------------------------
// Fallback (ws too small for afT): fused gather + LDS-epilogue transform.
// ---------------------------------------------------------------------------
__global__ __launch_bounds__(256) void gather_transform_kernel(
    const float* __restrict__ atom_fea,
    const int*   __restrict__ nbr_idx,
    const float* __restrict__ s,
    const float* __restrict__ tp_w,
    float* __restrict__ out)
{
    __shared__ float accL[64 * C_DIM];
    const int tid = threadIdx.x;
    const int c  = tid & 63;
    const int rq = tid >> 6;

    float Tc[64];
    #pragma unroll
    for (int k = 0; k < 64; ++k) Tc[k] = tp_w[k * 64 + c] * 0.125f;

    const int row0 = blockIdx.x * 64;
    for (int i = 0; i < 16; ++i) {
        int r = row0 + rq * 16 + i;
        float a = 0.0f;
        if (r < N_ROWS) {
            const int*   ir = nbr_idx + (long)r * M_NBR;
            const float* sr = s       + (long)r * M_NBR;
            #pragma unroll
            for (int j = 0; j < M_NBR; ++j)
                a = fmaf(sr[j], atom_fea[(long)ir[j] * C_DIM + c], a);
        }
        accL[(rq * 16 + i) * C_DIM + c] = a;
    }
    __syncthreads();
    for (int i = 0; i < 16; ++i) {
        int rl = rq * 16 + i;
        int r  = row0 + rl;
        if (r >= N_ROWS) continue;
        const float* ar = accL + rl * C_DIM;
        float o = 0.0f;
        #pragma unroll
        for (int k = 0; k < 64; ++k) o = fmaf(ar[k], Tc[k], o);
        out[(long)r * C_DIM + c] = o;
    }
}

extern "C" void kernel_launch(void* const* d_in, const int* in_sizes, int n_in,
                              void* d_out, int out_size, void* d_ws, size_t ws_size,
                              hipStream_t stream) {
    const float* atom_fea = (const float*)d_in[0];
    const float* nbr_fea  = (const float*)d_in[1];
    const int*   nbr_idx  = (const int*)  d_in[2];
    // d_in[3] = pos : dead (only the constant l=0 SH channel couples)
    const float* w1   = (const float*)d_in[4];
    const float* b1   = (const float*)d_in[5];
    const float* w2   = (const float*)d_in[6];
    const float* b2   = (const float*)d_in[7];
    const float* tp_w = (const float*)d_in[8];

    // ws layout: [bpack 8KB][s 4.8MB][afT16 12.8MB]
    _Float16* bpack = (_Float16*)d_ws;
    float*    s     = (float*)((char*)d_ws + 8192);
    float*    out   = (float*)d_out;

    const size_t sBytes    = (size_t)E_TOT * sizeof(float);              // 4,800,000
    const size_t afTBytes  = (size_t)N_ROWS * C_DIM * sizeof(_Float16);  // 12.8 MB

    prep_edge_B<<<1, 384, 0, stream>>>(w1, b1, bpack);

    const int blocksA = E_TOT / 128;                 // 9375, exact
    edge_mlp_mfma_kernel<<<blocksA, 256, 0, stream>>>(nbr_fea, bpack, w2, b2, s);

    if (ws_size >= 8192 + sBytes + afTBytes) {
        _Float16* afT = (_Float16*)((char*)d_ws + 8192 + sBytes);
        const int blocksT = (N_ROWS + 127) / 128;    // 782
        atom_transform_mfma_kernel<<<blocksT, 256, 0, stream>>>(atom_fea, tp_w, afT);
        const int blocksG = N_ROWS / 32;             // 3125, exact
        gather_kernel<<<blocksG, 256, 0, stream>>>(afT, nbr_idx, s, out);
    } else {
        const int blocksB = (N_ROWS + 63) / 64;
        gather_transform_kernel<<<blocksB, 256, 0, stream>>>(atom_fea, nbr_idx, s, tp_w, out);
    }
}

// Round 8
// 341.099 us; speedup vs baseline: 1.2766x; 1.0156x over previous
//
#include <hip/hip_runtime.h>

#define N_ROWS 100000
#define M_NBR  12
#define C_DIM  64
#define F_DIM  41
#define E_TOT  (N_ROWS * M_NBR)

typedef _Float16 half8 __attribute__((ext_vector_type(8)));
typedef _Float16 half4v __attribute__((ext_vector_type(4)));
typedef float float4v __attribute__((ext_vector_type(4)));

#define EPITCH   68   // fp32 LDS pitch (B1): 272B, 16B-aligned
#define EPITCH_H 72   // fp16 LDS pitch (edge): 144B, 16B-aligned

// fp16 Dekker split (B1 only)
__device__ __forceinline__ void split8(const float (&v)[8], half8& hi, half8& lo) {
    #pragma unroll
    for (int i = 0; i < 8; ++i) {
        const _Float16 h = (_Float16)v[i];
        hi[i] = h;
        lo[i] = (_Float16)(v[i] - (float)h);
    }
}

// 16-lane rotate-allreduce step on the VALU (DPP row_ror), replacing
// __shfl_xor's ds_swizzle: reduction group == DPP 16-lane row exactly.
#define DPP_ROR_ADD(v, CTRL) \
    ((v) + __int_as_float(__builtin_amdgcn_update_dpp(0, __float_as_int(v), (CTRL), 0xF, 0xF, true)))

// ---------------------------------------------------------------------------
// Prep (standalone; used by fallback path only — main path folds this work
// into the B1 launch): pack W1^T (+ b1 as k=41 row) into fp16 B-fragments.
// ---------------------------------------------------------------------------
__global__ __launch_bounds__(384) void prep_edge_B(
    const float* __restrict__ w1,   // [F, F]
    const float* __restrict__ b1,   // [F]
    _Float16* __restrict__ bpack)   // [3*2*64*8]
{
    const int tid  = threadIdx.x;
    const int wid  = tid >> 6;           // 0..5
    const int lane = tid & 63;
    const int nt   = wid >> 1;
    const int ks   = wid & 1;
    const int n15  = lane & 15, g = lane >> 4;

    const int j = nt * 16 + n15;
    half8 v;
    #pragma unroll
    for (int i = 0; i < 8; ++i) {
        const int k = ks * 32 + g * 8 + i;
        float f = 0.0f;
        if (j < F_DIM) {
            if (k < F_DIM)       f = w1[k * F_DIM + j];
            else if (k == F_DIM) f = b1[j];       // bias folded as row 41
        }
        v[i] = (_Float16)f;
    }
    *(half8*)(bpack + ((nt * 2 + ks) * 64 + lane) * 8) = v;
}

// ---------------------------------------------------------------------------
// Kernel A v5: identical to v4 except the epilogue 16-lane reduction now
// runs on the VALU via DPP row_ror rotate-allreduce instead of __shfl_xor.
// DS-pipe census showed the 128 shuffle wave-instr/block (~770 cyc) were the
// largest DS consumer; DPP removes them entirely (reassociation-only change).
// ---------------------------------------------------------------------------
__global__ __launch_bounds__(256) void edge_mlp_mfma_kernel(
    const float* __restrict__ nbr_fea,   // [E, F]
    const _Float16* __restrict__ bpack,  // packed B fragments (+bias row)
    const float* __restrict__ w2,        // [F, 9]
    const float* __restrict__ b2,        // [9]
    float* __restrict__ s_out)           // [E]
{
    __shared__ float lsf[128 * F_DIM];           // 20992 B; aliased fp16 pitch-72 after
    _Float16* lsh = (_Float16*)lsf;              // fp16 rows use bytes [0, 18432)

    const int tid  = threadIdx.x;
    const int lane = tid & 63;
    const int wv   = tid >> 6;
    const int n15  = lane & 15;
    const int g    = lane >> 4;
    const long base = (long)blockIdx.x * 128;

    // ---- B fragments: 6 coalesced 16B loads (overlap the staging below)
    half8 Bh[3][2];
    #pragma unroll
    for (int nt = 0; nt < 3; ++nt)
        #pragma unroll
        for (int ks = 0; ks < 2; ++ks)
            Bh[nt][ks] = *(const half8*)(bpack + ((nt * 2 + ks) * 64 + lane) * 8);

    // ---- phase A: linear coalesced copy, zero arithmetic
    {
        const float4* g4 = (const float4*)(nbr_fea + base * F_DIM);  // 20992B/blk: 16B-aligned
        float4* l4 = (float4*)lsf;
        for (int i = tid; i < 1312; i += 256) l4[i] = g4[i];
    }
    __syncthreads();

    // ---- phase B: row-owner reads its packed row (imm-offset ds_read_b32)
    float xr[F_DIM];
    const bool owner = tid < 128;
    if (owner) {
        const float* src = lsf + tid * F_DIM;
        #pragma unroll
        for (int k = 0; k < F_DIM; ++k) xr[k] = src[k];
    }
    __syncthreads();   // all packed reads done before fp16 overwrite

    // ---- phase C: cvt + write fp16 row (pitch 72), bias/zeros baked in
    if (owner) {
        half8 hv[8];
        #pragma unroll
        for (int q = 0; q < 8; ++q) {
            #pragma unroll
            for (int i = 0; i < 8; ++i) {
                const int k = q * 8 + i;
                _Float16 h = (_Float16)0.0f;
                if (k < F_DIM)       h = (_Float16)xr[k];   // RTN cast
                else if (k == F_DIM) h = (_Float16)1.0f;    // bias column
                hv[q][i] = h;
            }
        }
        _Float16* dst = lsh + tid * EPITCH_H;
        #pragma unroll
        for (int q = 0; q < 8; ++q)
            *(half8*)(dst + q * 8) = hv[q];
    }
    __syncthreads();

    float4v acc[2][3];
    #pragma unroll
    for (int mt = 0; mt < 2; ++mt)
        #pragma unroll
        for (int nt = 0; nt < 3; ++nt)
            #pragma unroll
            for (int i = 0; i < 4; ++i) acc[mt][nt][i] = 0.0f;

    // ---- main: 1 ds_read_b128 + 3 MFMA per (mt,ks)
    #pragma unroll
    for (int mt = 0; mt < 2; ++mt) {
        const int row = wv * 32 + mt * 16 + n15;
        #pragma unroll
        for (int ks = 0; ks < 2; ++ks) {
            const half8 a = *(const half8*)(lsh + row * EPITCH_H + ks * 32 + g * 8);  // 16B-aligned
            #pragma unroll
            for (int nt = 0; nt < 3; ++nt)
                acc[mt][nt] = __builtin_amdgcn_mfma_f32_16x16x32_f16(a, Bh[nt][ks], acc[mt][nt], 0, 0, 0);
        }
    }

    // ---- epilogue: softplus (h includes b1) -> w2-dot -> DPP rotate-allreduce
    float w2v[3];
    #pragma unroll
    for (int nt = 0; nt < 3; ++nt) {
        const int j = nt * 16 + n15;
        w2v[nt] = (j < F_DIM) ? w2[j * 9] : 0.0f;   // zero kills pad lanes
    }
    const float b2v   = b2[0];
    const float scale = 0.28209479177387814f / 12.0f;

    #pragma unroll
    for (int mt = 0; mt < 2; ++mt) {
        float p[4];
        #pragma unroll
        for (int r = 0; r < 4; ++r) {
            float sum = 0.0f;
            #pragma unroll
            for (int nt = 0; nt < 3; ++nt) {
                const float v  = acc[mt][nt][r];
                const float sp = fmaxf(v, 0.0f) + __logf(1.0f + __expf(-fabsf(v)));
                sum = fmaf(sp, w2v[nt], sum);
            }
            p[r] = sum;
        }
        // 16-lane allreduce on VALU: v += ror(v, 1,2,4,8) within each DPP row
        #pragma unroll
        for (int r = 0; r < 4; ++r) {
            float v = p[r];
            v = DPP_ROR_ADD(v, 0x121);   // row_ror:1
            v = DPP_ROR_ADD(v, 0x122);   // row_ror:2
            v = DPP_ROR_ADD(v, 0x124);   // row_ror:4
            v = DPP_ROR_ADD(v, 0x128);   // row_ror:8
            p[r] = v;
        }
        if (n15 == 0) {
            #pragma unroll
            for (int r = 0; r < 4; ++r) {
                const long e = base + wv * 32 + mt * 16 + g * 4 + r;
                s_out[e] = (p[r] + b2v) * scale;
            }
        }
    }
}

// ---------------------------------------------------------------------------
// Kernel B1 v4 (MFMA + hosted prep): afT = atom_fea @ (tp_w/8), fp16 out.
// The LAST block packs bpack (prep work folded here: B1 has no bpack
// dependency, and edge launches after B1 -> ordering guarantees visibility).
// Saves one serial kernel launch. GEMM body unchanged.
// ---------------------------------------------------------------------------
__global__ __launch_bounds__(256) void atom_transform_mfma_kernel(
    const float* __restrict__ atom_fea,  // [N, C]
    const float* __restrict__ tp_w,      // [C, C]
    const float* __restrict__ w1,        // [F, F]  (for prep block)
    const float* __restrict__ b1,        // [F]     (for prep block)
    _Float16* __restrict__ afT,          // [N, C] fp16
    _Float16* __restrict__ bpack)        // [3*2*64*8]
{
    if (blockIdx.x == gridDim.x - 1) {
        // ---- prep block: 6 fragments, 4 waves -> fi = wid, wid+4
        const int tid  = threadIdx.x;
        const int lane = tid & 63;
        const int n15  = lane & 15, g = lane >> 4;
        for (int fi = tid >> 6; fi < 6; fi += 4) {
            const int nt = fi >> 1;
            const int ks = fi & 1;
            const int j = nt * 16 + n15;
            half8 v;
            #pragma unroll
            for (int i = 0; i < 8; ++i) {
                const int k = ks * 32 + g * 8 + i;
                float f = 0.0f;
                if (j < F_DIM) {
                    if (k < F_DIM)       f = w1[k * F_DIM + j];
                    else if (k == F_DIM) f = b1[j];
                }
                v[i] = (_Float16)f;
            }
            *(half8*)(bpack + ((nt * 2 + ks) * 64 + lane) * 8) = v;
        }
        return;
    }

    __shared__ float lx[128 * EPITCH];   // 34816 B

    const int tid  = threadIdx.x;
    const int lane = tid & 63;
    const int wv   = tid >> 6;
    const int n15  = lane & 15;
    const int g    = lane >> 4;
    const long row0 = (long)blockIdx.x * 128;
    const int nrow = (N_ROWS - row0) < 128 ? (int)(N_ROWS - row0) : 128;

    {
        const float4* g4 = (const float4*)(atom_fea + row0 * C_DIM);
        for (int i = tid; i < 128 * 16; i += 256) {
            const int r  = i >> 4;
            const int c4 = i & 15;
            const float4 v = (r < nrow) ? g4[r * 16 + c4] : make_float4(0.f, 0.f, 0.f, 0.f);
            *(float4*)(lx + r * EPITCH + c4 * 4) = v;
        }
    }
    __syncthreads();

    float4v acc[2][4];
    #pragma unroll
    for (int mt = 0; mt < 2; ++mt)
        #pragma unroll
        for (int nt = 0; nt < 4; ++nt)
            #pragma unroll
            for (int i = 0; i < 4; ++i) acc[mt][nt][i] = 0.0f;

    #pragma unroll
    for (int ks = 0; ks < 2; ++ks) {
        half8 Th[4], Tl[4];
        #pragma unroll
        for (int nt = 0; nt < 4; ++nt) {
            const int j = nt * 16 + n15;
            float v[8];
            #pragma unroll
            for (int i = 0; i < 8; ++i) {
                const int k = ks * 32 + g * 8 + i;
                v[i] = tp_w[k * C_DIM + j] * 0.125f;
            }
            split8(v, Th[nt], Tl[nt]);
        }
        #pragma unroll
        for (int mt = 0; mt < 2; ++mt) {
            const int row = wv * 32 + mt * 16 + n15;
            const float* src = lx + row * EPITCH + ks * 32 + g * 8;
            float av[8];
            *(float4*)(av)     = *(const float4*)(src);
            *(float4*)(av + 4) = *(const float4*)(src + 4);
            half8 ah, al;
            split8(av, ah, al);
            #pragma unroll
            for (int nt = 0; nt < 4; ++nt) {
                acc[mt][nt] = __builtin_amdgcn_mfma_f32_16x16x32_f16(ah, Th[nt], acc[mt][nt], 0, 0, 0);
                acc[mt][nt] = __builtin_amdgcn_mfma_f32_16x16x32_f16(al, Th[nt], acc[mt][nt], 0, 0, 0);
                acc[mt][nt] = __builtin_amdgcn_mfma_f32_16x16x32_f16(ah, Tl[nt], acc[mt][nt], 0, 0, 0);
            }
        }
    }

    #pragma unroll
    for (int mt = 0; mt < 2; ++mt) {
        #pragma unroll
        for (int r = 0; r < 4; ++r) {
            const long row = row0 + wv * 32 + mt * 16 + g * 4 + r;
            if (row < N_ROWS) {
                #pragma unroll
                for (int nt = 0; nt < 4; ++nt)
                    afT[row * C_DIM + nt * 16 + n15] = (_Float16)acc[mt][nt][r];
            }
        }
    }
}

// ---------------------------------------------------------------------------
// Kernel B2 v2: out[r][:] = sum_j s_rj * afT16[idx_rj][:]. Unchanged.
// ---------------------------------------------------------------------------
__global__ __launch_bounds__(256) void gather_kernel(
    const _Float16* __restrict__ afT,    // [N, C] fp16
    const int*   __restrict__ nbr_idx,   // [N, M]
    const float* __restrict__ s,         // [E]
    float* __restrict__ out)             // [N, C]
{
    const int tid  = threadIdx.x;
    const int lane = tid & 63;
    const int wv   = tid >> 6;
    const int q    = lane >> 4;          // row-in-chunk 0..3
    const int c4   = (lane & 15) * 4;    // channel offset

    const int row0 = blockIdx.x * 32 + wv * 8;   // 8 rows per wave (N = 3125*32)

    #pragma unroll
    for (int ch = 0; ch < 2; ++ch) {
        int r = row0 + ch * 4 + q;
        const int*   ir = nbr_idx + r * M_NBR;
        const float* sr = s       + r * M_NBR;
        float4 acc = make_float4(0.f, 0.f, 0.f, 0.f);
        #pragma unroll
        for (int j = 0; j < M_NBR; ++j) {
            int   idx = ir[j];
            float sv  = sr[j];
            const half4v a = *(const half4v*)(afT + (long)idx * C_DIM + c4);  // 8B-aligned
            acc.x = fmaf(sv, (float)a[0], acc.x);
            acc.y = fmaf(sv, (float)a[1], acc.y);
            acc.z = fmaf(sv, (float)a[2], acc.z);
            acc.w = fmaf(sv, (float)a[3], acc.w);
        }
        *(float4*)(out + (long)r * C_DIM + c4) = acc;   // coalesced
    }
}

// ---------------------------------------------------------------------------
// Fallback (ws too small for afT): fused gather + LDS-epilogue transform.
// ---------------------------------------------------------------------------
__global__ __launch_bounds__(256) void gather_transform_kernel(
    const float* __restrict__ atom_fea,
    const int*   __restrict__ nbr_idx,
    const float* __restrict__ s,
    const float* __restrict__ tp_w,
    float* __restrict__ out)
{
    __shared__ float accL[64 * C_DIM];
    const int tid = threadIdx.x;
    const int c  = tid & 63;
    const int rq = tid >> 6;

    float Tc[64];
    #pragma unroll
    for (int k = 0; k < 64; ++k) Tc[k] = tp_w[k * 64 + c] * 0.125f;

    const int row0 = blockIdx.x * 64;
    for (int i = 0; i < 16; ++i) {
        int r = row0 + rq * 16 + i;
        float a = 0.0f;
        if (r < N_ROWS) {
            const int*   ir = nbr_idx + (long)r * M_NBR;
            const float* sr = s       + (long)r * M_NBR;
            #pragma unroll
            for (int j = 0; j < M_NBR; ++j)
                a = fmaf(sr[j], atom_fea[(long)ir[j] * C_DIM + c], a);
        }
        accL[(rq * 16 + i) * C_DIM + c] = a;
    }
    __syncthreads();
    for (int i = 0; i < 16; ++i) {
        int rl = rq * 16 + i;
        int r  = row0 + rl;
        if (r >= N_ROWS) continue;
        const float* ar = accL + rl * C_DIM;
        float o = 0.0f;
        #pragma unroll
        for (int k = 0; k < 64; ++k) o = fmaf(ar[k], Tc[k], o);
        out[(long)r * C_DIM + c] = o;
    }
}

extern "C" void kernel_launch(void* const* d_in, const int* in_sizes, int n_in,
                              void* d_out, int out_size, void* d_ws, size_t ws_size,
                              hipStream_t stream) {
    const float* atom_fea = (const float*)d_in[0];
    const float* nbr_fea  = (const float*)d_in[1];
    const int*   nbr_idx  = (const int*)  d_in[2];
    // d_in[3] = pos : dead (only the constant l=0 SH channel couples)
    const float* w1   = (const float*)d_in[4];
    const float* b1   = (const float*)d_in[5];
    const float* w2   = (const float*)d_in[6];
    const float* b2   = (const float*)d_in[7];
    const float* tp_w = (const float*)d_in[8];

    // ws layout: [bpack 8KB][s 4.8MB][afT16 12.8MB]
    _Float16* bpack = (_Float16*)d_ws;
    float*    s     = (float*)((char*)d_ws + 8192);
    float*    out   = (float*)d_out;

    const size_t sBytes    = (size_t)E_TOT * sizeof(float);              // 4,800,000
    const size_t afTBytes  = (size_t)N_ROWS * C_DIM * sizeof(_Float16);  // 12.8 MB

    if (ws_size >= 8192 + sBytes + afTBytes) {
        _Float16* afT = (_Float16*)((char*)d_ws + 8192 + sBytes);
        // B1 (+prep in last block) -> edge -> B2: edge sees bpack via kernel
        // ordering; B1 itself has no bpack dependency.
        const int blocksT = (N_ROWS + 127) / 128 + 1;   // 782 rows-blocks + 1 prep
        atom_transform_mfma_kernel<<<blocksT, 256, 0, stream>>>(atom_fea, tp_w, w1, b1, afT, bpack);

        const int blocksA = E_TOT / 128;                // 9375, exact
        edge_mlp_mfma_kernel<<<blocksA, 256, 0, stream>>>(nbr_fea, bpack, w2, b2, s);

        const int blocksG = N_ROWS / 32;                // 3125, exact
        gather_kernel<<<blocksG, 256, 0, stream>>>(afT, nbr_idx, s, out);
    } else {
        prep_edge_B<<<1, 384, 0, stream>>>(w1, b1, bpack);
        const int blocksA = E_TOT / 128;
        edge_mlp_mfma_kernel<<<blocksA, 256, 0, stream>>>(nbr_fea, bpack, w2, b2, s);
        const int blocksB = (N_ROWS + 63) / 64;
        gather_transform_kernel<<<blocksB, 256, 0, stream>>>(atom_fea, nbr_idx, s, tp_w, out);
    }
}

// Round 9
// 339.031 us; speedup vs baseline: 1.2843x; 1.0061x over previous
//
#include <hip/hip_runtime.h>

#define N_ROWS 100000
#define M_NBR  12
#define C_DIM  64
#define F_DIM  41
#define E_TOT  (N_ROWS * M_NBR)

typedef _Float16 half8 __attribute__((ext_vector_type(8)));
typedef _Float16 half4v __attribute__((ext_vector_type(4)));
typedef float float4v __attribute__((ext_vector_type(4)));

#define EPITCH_H 72   // fp16 LDS pitch (edge): 144B, 16B-aligned, 2-way banks on b128

// fp16 Dekker split (B1 only)
__device__ __forceinline__ void split8(const float (&v)[8], half8& hi, half8& lo) {
    #pragma unroll
    for (int i = 0; i < 8; ++i) {
        const _Float16 h = (_Float16)v[i];
        hi[i] = h;
        lo[i] = (_Float16)(v[i] - (float)h);
    }
}

// 16-lane rotate-allreduce on the VALU (DPP row_ror); groups == DPP rows.
#define DPP_ROR_ADD(v, CTRL) \
    ((v) + __int_as_float(__builtin_amdgcn_update_dpp(0, __float_as_int(v), (CTRL), 0xF, 0xF, true)))

// ---------------------------------------------------------------------------
// Prep: pack W1^T (+ b1 as k=41 row) into fp16 B-fragments, once. Standalone
// micro-launch again (it must precede the merged kernel, whose edge blocks
// consume bpack).
// ---------------------------------------------------------------------------
__global__ __launch_bounds__(384) void prep_edge_B(
    const float* __restrict__ w1,   // [F, F]
    const float* __restrict__ b1,   // [F]
    _Float16* __restrict__ bpack)   // [3*2*64*8]
{
    const int tid  = threadIdx.x;
    const int wid  = tid >> 6;           // 0..5
    const int lane = tid & 63;
    const int nt   = wid >> 1;
    const int ks   = wid & 1;
    const int n15  = lane & 15, g = lane >> 4;

    const int j = nt * 16 + n15;
    half8 v;
    #pragma unroll
    for (int i = 0; i < 8; ++i) {
        const int k = ks * 32 + g * 8 + i;
        float f = 0.0f;
        if (j < F_DIM) {
            if (k < F_DIM)       f = w1[k * F_DIM + j];
            else if (k == F_DIM) f = b1[j];       // bias folded as row 41
        }
        v[i] = (_Float16)f;
    }
    *(half8*)(bpack + ((nt * 2 + ks) * 64 + lane) * 8) = v;
}

// ---------------------------------------------------------------------------
// B1 v5 (device fn, LDS-FREE): atom_fea rows are 256B-aligned, so each lane
// loads its A-fragment directly from global as 2x dwordx4 (the wave's
// (mt,ks) loop consumes every byte of the 16-row x 256B panel -> L1/L2
// absorb the interleave). Deletes the 35KB LDS bounce + barrier; enables
// folding B1 into the edge launch. Arithmetic bit-identical to v4
// (same floats -> same split8 -> same MFMA order).
// ---------------------------------------------------------------------------
__device__ __forceinline__ void atom_transform_direct(
    const float* __restrict__ atom_fea,  // [N, C]
    const float* __restrict__ tp_w,      // [C, C]
    _Float16* __restrict__ afT,          // [N, C] fp16
    const int bid)
{
    const int tid  = threadIdx.x;
    const int lane = tid & 63;
    const int wv   = tid >> 6;
    const int n15  = lane & 15;
    const int g    = lane >> 4;
    const long row0 = (long)bid * 128;

    float4v acc[2][4];
    #pragma unroll
    for (int mt = 0; mt < 2; ++mt)
        #pragma unroll
        for (int nt = 0; nt < 4; ++nt)
            #pragma unroll
            for (int i = 0; i < 4; ++i) acc[mt][nt][i] = 0.0f;

    #pragma unroll
    for (int ks = 0; ks < 2; ++ks) {
        half8 Th[4], Tl[4];
        #pragma unroll
        for (int nt = 0; nt < 4; ++nt) {
            const int j = nt * 16 + n15;
            float v[8];
            #pragma unroll
            for (int i = 0; i < 8; ++i) {
                const int k = ks * 32 + g * 8 + i;
                v[i] = tp_w[k * C_DIM + j] * 0.125f;
            }
            split8(v, Th[nt], Tl[nt]);
        }
        #pragma unroll
        for (int mt = 0; mt < 2; ++mt) {
            long row = row0 + wv * 32 + mt * 16 + n15;
            if (row > (long)N_ROWS - 1) row = (long)N_ROWS - 1;   // clamp loads; stores guarded
            const float* src = atom_fea + row * C_DIM + ks * 32 + g * 8;  // 16B-aligned
            float av[8];
            *(float4*)(av)     = *(const float4*)(src);
            *(float4*)(av + 4) = *(const float4*)(src + 4);
            half8 ah, al;
            split8(av, ah, al);
            #pragma unroll
            for (int nt = 0; nt < 4; ++nt) {
                acc[mt][nt] = __builtin_amdgcn_mfma_f32_16x16x32_f16(ah, Th[nt], acc[mt][nt], 0, 0, 0);
                acc[mt][nt] = __builtin_amdgcn_mfma_f32_16x16x32_f16(al, Th[nt], acc[mt][nt], 0, 0, 0);
                acc[mt][nt] = __builtin_amdgcn_mfma_f32_16x16x32_f16(ah, Tl[nt], acc[mt][nt], 0, 0, 0);
            }
        }
    }

    #pragma unroll
    for (int mt = 0; mt < 2; ++mt) {
        #pragma unroll
        for (int r = 0; r < 4; ++r) {
            const long row = row0 + wv * 32 + mt * 16 + g * 4 + r;
            if (row < N_ROWS) {
                #pragma unroll
                for (int nt = 0; nt < 4; ++nt)
                    afT[row * C_DIM + nt * 16 + n15] = (_Float16)acc[mt][nt][r];
            }
        }
    }
}

// ---------------------------------------------------------------------------
// Merged kernel: blocks [0, nT) run B1-direct (memory-heavy, scheduled
// early); blocks [nT, nT+9375) run edge v5 (bit-identical to round 8).
// Block-level role split -> no wave divergence. Shared mem = edge's 21KB
// only (B1 path uses none), so edge occupancy (7 blocks/CU) is preserved.
// ---------------------------------------------------------------------------
__global__ __launch_bounds__(256) void fused_edge_atom_kernel(
    const float* __restrict__ nbr_fea,   // [E, F]
    const _Float16* __restrict__ bpack,  // packed B fragments (+bias row)
    const float* __restrict__ w2,        // [F, 9]
    const float* __restrict__ b2,        // [9]
    float* __restrict__ s_out,           // [E]
    const float* __restrict__ atom_fea,  // [N, C]
    const float* __restrict__ tp_w,      // [C, C]
    _Float16* __restrict__ afT,          // [N, C] fp16
    const int nT)                        // # B1 blocks (782)
{
    __shared__ float lsf[128 * F_DIM];           // 20992 B; aliased fp16 pitch-72
    _Float16* lsh = (_Float16*)lsf;

    if ((int)blockIdx.x < nT) {
        atom_transform_direct(atom_fea, tp_w, afT, blockIdx.x);
        return;
    }

    const int tid  = threadIdx.x;
    const int lane = tid & 63;
    const int wv   = tid >> 6;
    const int n15  = lane & 15;
    const int g    = lane >> 4;
    const long base = (long)(blockIdx.x - nT) * 128;

    // ---- B fragments: 6 coalesced 16B loads (overlap the staging below)
    half8 Bh[3][2];
    #pragma unroll
    for (int nt = 0; nt < 3; ++nt)
        #pragma unroll
        for (int ks = 0; ks < 2; ++ks)
            Bh[nt][ks] = *(const half8*)(bpack + ((nt * 2 + ks) * 64 + lane) * 8);

    // ---- phase A: linear coalesced copy, zero arithmetic
    {
        const float4* g4 = (const float4*)(nbr_fea + base * F_DIM);  // 20992B/blk: 16B-aligned
        float4* l4 = (float4*)lsf;
        for (int i = tid; i < 1312; i += 256) l4[i] = g4[i];
    }
    __syncthreads();

    // ---- phase B: row-owner reads its packed row (imm-offset ds_read_b32)
    float xr[F_DIM];
    const bool owner = tid < 128;
    if (owner) {
        const float* src = lsf + tid * F_DIM;
        #pragma unroll
        for (int k = 0; k < F_DIM; ++k) xr[k] = src[k];
    }
    __syncthreads();   // all packed reads done before fp16 overwrite

    // ---- phase C: cvt + write fp16 row (pitch 72), bias/zeros baked in
    if (owner) {
        half8 hv[8];
        #pragma unroll
        for (int q = 0; q < 8; ++q) {
            #pragma unroll
            for (int i = 0; i < 8; ++i) {
                const int k = q * 8 + i;
                _Float16 h = (_Float16)0.0f;
                if (k < F_DIM)       h = (_Float16)xr[k];   // RTN cast
                else if (k == F_DIM) h = (_Float16)1.0f;    // bias column
                hv[q][i] = h;
            }
        }
        _Float16* dst = lsh + tid * EPITCH_H;
        #pragma unroll
        for (int q = 0; q < 8; ++q)
            *(half8*)(dst + q * 8) = hv[q];
    }
    __syncthreads();

    float4v acc[2][3];
    #pragma unroll
    for (int mt = 0; mt < 2; ++mt)
        #pragma unroll
        for (int nt = 0; nt < 3; ++nt)
            #pragma unroll
            for (int i = 0; i < 4; ++i) acc[mt][nt][i] = 0.0f;

    // ---- main: 1 ds_read_b128 + 3 MFMA per (mt,ks)
    #pragma unroll
    for (int mt = 0; mt < 2; ++mt) {
        const int row = wv * 32 + mt * 16 + n15;
        #pragma unroll
        for (int ks = 0; ks < 2; ++ks) {
            const half8 a = *(const half8*)(lsh + row * EPITCH_H + ks * 32 + g * 8);  // 16B-aligned
            #pragma unroll
            for (int nt = 0; nt < 3; ++nt)
                acc[mt][nt] = __builtin_amdgcn_mfma_f32_16x16x32_f16(a, Bh[nt][ks], acc[mt][nt], 0, 0, 0);
        }
    }

    // ---- epilogue: softplus (h includes b1) -> w2-dot -> DPP rotate-allreduce
    float w2v[3];
    #pragma unroll
    for (int nt = 0; nt < 3; ++nt) {
        const int j = nt * 16 + n15;
        w2v[nt] = (j < F_DIM) ? w2[j * 9] : 0.0f;   // zero kills pad lanes
    }
    const float b2v   = b2[0];
    const float scale = 0.28209479177387814f / 12.0f;

    #pragma unroll
    for (int mt = 0; mt < 2; ++mt) {
        float p[4];
        #pragma unroll
        for (int r = 0; r < 4; ++r) {
            float sum = 0.0f;
            #pragma unroll
            for (int nt = 0; nt < 3; ++nt) {
                const float v  = acc[mt][nt][r];
                const float sp = fmaxf(v, 0.0f) + __logf(1.0f + __expf(-fabsf(v)));
                sum = fmaf(sp, w2v[nt], sum);
            }
            p[r] = sum;
        }
        #pragma unroll
        for (int r = 0; r < 4; ++r) {
            float v = p[r];
            v = DPP_ROR_ADD(v, 0x121);   // row_ror:1
            v = DPP_ROR_ADD(v, 0x122);   // row_ror:2
            v = DPP_ROR_ADD(v, 0x124);   // row_ror:4
            v = DPP_ROR_ADD(v, 0x128);   // row_ror:8
            p[r] = v;
        }
        if (n15 == 0) {
            #pragma unroll
            for (int r = 0; r < 4; ++r) {
                const long e = base + wv * 32 + mt * 16 + g * 4 + r;
                s_out[e] = (p[r] + b2v) * scale;
            }
        }
    }
}

// ---------------------------------------------------------------------------
// Kernel B2 v2: out[r][:] = sum_j s_rj * afT16[idx_rj][:]. Unchanged.
// ---------------------------------------------------------------------------
__global__ __launch_bounds__(256) void gather_kernel(
    const _Float16* __restrict__ afT,    // [N, C] fp16
    const int*   __restrict__ nbr_idx,   // [N, M]
    const float* __restrict__ s,         // [E]
    float* __restrict__ out)             // [N, C]
{
    const int tid  = threadIdx.x;
    const int lane = tid & 63;
    const int wv   = tid >> 6;
    const int q    = lane >> 4;          // row-in-chunk 0..3
    const int c4   = (lane & 15) * 4;    // channel offset

    const int row0 = blockIdx.x * 32 + wv * 8;   // 8 rows per wave (N = 3125*32)

    #pragma unroll
    for (int ch = 0; ch < 2; ++ch) {
        int r = row0 + ch * 4 + q;
        const int*   ir = nbr_idx + r * M_NBR;
        const float* sr = s       + r * M_NBR;
        float4 acc = make_float4(0.f, 0.f, 0.f, 0.f);
        #pragma unroll
        for (int j = 0; j < M_NBR; ++j) {
            int   idx = ir[j];
            float sv  = sr[j];
            const half4v a = *(const half4v*)(afT + (long)idx * C_DIM + c4);  // 8B-aligned
            acc.x = fmaf(sv, (float)a[0], acc.x);
            acc.y = fmaf(sv, (float)a[1], acc.y);
            acc.z = fmaf(sv, (float)a[2], acc.z);
            acc.w = fmaf(sv, (float)a[3], acc.w);
        }
        *(float4*)(out + (long)r * C_DIM + c4) = acc;   // coalesced
    }
}

// ---------------------------------------------------------------------------
// Fallback path kernels (ws too small for afT).
// ---------------------------------------------------------------------------
__global__ __launch_bounds__(256) void edge_mlp_mfma_kernel(
    const float* __restrict__ nbr_fea,
    const _Float16* __restrict__ bpack,
    const float* __restrict__ w2,
    const float* __restrict__ b2,
    float* __restrict__ s_out)
{
    // thin wrapper over the merged kernel's edge path via nT=0 semantics is
    // not possible across launches; replicate by calling with nT=0:
    // (kept as a separate instantiation for the fallback branch)
    // -- body identical to fused_edge_atom_kernel's edge path --
    __shared__ float lsf[128 * F_DIM];
    _Float16* lsh = (_Float16*)lsf;
    const int tid  = threadIdx.x;
    const int lane = tid & 63;
    const int wv   = tid >> 6;
    const int n15  = lane & 15;
    const int g    = lane >> 4;
    const long base = (long)blockIdx.x * 128;

    half8 Bh[3][2];
    #pragma unroll
    for (int nt = 0; nt < 3; ++nt)
        #pragma unroll
        for (int ks = 0; ks < 2; ++ks)
            Bh[nt][ks] = *(const half8*)(bpack + ((nt * 2 + ks) * 64 + lane) * 8);

    {
        const float4* g4 = (const float4*)(nbr_fea + base * F_DIM);
        float4* l4 = (float4*)lsf;
        for (int i = tid; i < 1312; i += 256) l4[i] = g4[i];
    }
    __syncthreads();

    float xr[F_DIM];
    const bool owner = tid < 128;
    if (owner) {
        const float* src = lsf + tid * F_DIM;
        #pragma unroll
        for (int k = 0; k < F_DIM; ++k) xr[k] = src[k];
    }
    __syncthreads();

    if (owner) {
        half8 hv[8];
        #pragma unroll
        for (int q = 0; q < 8; ++q) {
            #pragma unroll
            for (int i = 0; i < 8; ++i) {
                const int k = q * 8 + i;
                _Float16 h = (_Float16)0.0f;
                if (k < F_DIM)       h = (_Float16)xr[k];
                else if (k == F_DIM) h = (_Float16)1.0f;
                hv[q][i] = h;
            }
        }
        _Float16* dst = lsh + tid * EPITCH_H;
        #pragma unroll
        for (int q = 0; q < 8; ++q)
            *(half8*)(dst + q * 8) = hv[q];
    }
    __syncthreads();

    float4v acc[2][3];
    #pragma unroll
    for (int mt = 0; mt < 2; ++mt)
        #pragma unroll
        for (int nt = 0; nt < 3; ++nt)
            #pragma unroll
            for (int i = 0; i < 4; ++i) acc[mt][nt][i] = 0.0f;

    #pragma unroll
    for (int mt = 0; mt < 2; ++mt) {
        const int row = wv * 32 + mt * 16 + n15;
        #pragma unroll
        for (int ks = 0; ks < 2; ++ks) {
            const half8 a = *(const half8*)(lsh + row * EPITCH_H + ks * 32 + g * 8);
            #pragma unroll
            for (int nt = 0; nt < 3; ++nt)
                acc[mt][nt] = __builtin_amdgcn_mfma_f32_16x16x32_f16(a, Bh[nt][ks], acc[mt][nt], 0, 0, 0);
        }
    }

    float w2v[3];
    #pragma unroll
    for (int nt = 0; nt < 3; ++nt) {
        const int j = nt * 16 + n15;
        w2v[nt] = (j < F_DIM) ? w2[j * 9] : 0.0f;
    }
    const float b2v   = b2[0];
    const float scale = 0.28209479177387814f / 12.0f;

    #pragma unroll
    for (int mt = 0; mt < 2; ++mt) {
        float p[4];
        #pragma unroll
        for (int r = 0; r < 4; ++r) {
            float sum = 0.0f;
            #pragma unroll
            for (int nt = 0; nt < 3; ++nt) {
                const float v  = acc[mt][nt][r];
                const float sp = fmaxf(v, 0.0f) + __logf(1.0f + __expf(-fabsf(v)));
                sum = fmaf(sp, w2v[nt], sum);
            }
            p[r] = sum;
        }
        #pragma unroll
        for (int r = 0; r < 4; ++r) {
            float v = p[r];
            v = DPP_ROR_ADD(v, 0x121);
            v = DPP_ROR_ADD(v, 0x122);
            v = DPP_ROR_ADD(v, 0x124);
            v = DPP_ROR_ADD(v, 0x128);
            p[r] = v;
        }
        if (n15 == 0) {
            #pragma unroll
            for (int r = 0; r < 4; ++r) {
                const long e = base + wv * 32 + mt * 16 + g * 4 + r;
                s_out[e] = (p[r] + b2v) * scale;
            }
        }
    }
}

__global__ __launch_bounds__(256) void gather_transform_kernel(
    const float* __restrict__ atom_fea,
    const int*   __restrict__ nbr_idx,
    const float* __restrict__ s,
    const float* __restrict__ tp_w,
    float* __restrict__ out)
{
    __shared__ float accL[64 * C_DIM];
    const int tid = threadIdx.x;
    const int c  = tid & 63;
    const int rq = tid >> 6;

    float Tc[64];
    #pragma unroll
    for (int k = 0; k < 64; ++k) Tc[k] = tp_w[k * 64 + c] * 0.125f;

    const int row0 = blockIdx.x * 64;
    for (int i = 0; i < 16; ++i) {
        int r = row0 + rq * 16 + i;
        float a = 0.0f;
        if (r < N_ROWS) {
            const int*   ir = nbr_idx + (long)r * M_NBR;
            const float* sr = s       + (long)r * M_NBR;
            #pragma unroll
            for (int j = 0; j < M_NBR; ++j)
                a = fmaf(sr[j], atom_fea[(long)ir[j] * C_DIM + c], a);
        }
        accL[(rq * 16 + i) * C_DIM + c] = a;
    }
    __syncthreads();
    for (int i = 0; i < 16; ++i) {
        int rl = rq * 16 + i;
        int r  = row0 + rl;
        if (r >= N_ROWS) continue;
        const float* ar = accL + rl * C_DIM;
        float o = 0.0f;
        #pragma unroll
        for (int k = 0; k < 64; ++k) o = fmaf(ar[k], Tc[k], o);
        out[(long)r * C_DIM + c] = o;
    }
}

extern "C" void kernel_launch(void* const* d_in, const int* in_sizes, int n_in,
                              void* d_out, int out_size, void* d_ws, size_t ws_size,
                              hipStream_t stream) {
    const float* atom_fea = (const float*)d_in[0];
    const float* nbr_fea  = (const float*)d_in[1];
    const int*   nbr_idx  = (const int*)  d_in[2];
    // d_in[3] = pos : dead (only the constant l=0 SH channel couples)
    const float* w1   = (const float*)d_in[4];
    const float* b1   = (const float*)d_in[5];
    const float* w2   = (const float*)d_in[6];
    const float* b2   = (const float*)d_in[7];
    const float* tp_w = (const float*)d_in[8];

    // ws layout: [bpack 8KB][s 4.8MB][afT16 12.8MB]
    _Float16* bpack = (_Float16*)d_ws;
    float*    s     = (float*)((char*)d_ws + 8192);
    float*    out   = (float*)d_out;

    const size_t sBytes    = (size_t)E_TOT * sizeof(float);              // 4,800,000
    const size_t afTBytes  = (size_t)N_ROWS * C_DIM * sizeof(_Float16);  // 12.8 MB

    prep_edge_B<<<1, 384, 0, stream>>>(w1, b1, bpack);

    if (ws_size >= 8192 + sBytes + afTBytes) {
        _Float16* afT = (_Float16*)((char*)d_ws + 8192 + sBytes);
        const int nT = (N_ROWS + 127) / 128;            // 782 B1 blocks
        const int blocksA = E_TOT / 128;                // 9375 edge blocks
        fused_edge_atom_kernel<<<nT + blocksA, 256, 0, stream>>>(
            nbr_fea, bpack, w2, b2, s, atom_fea, tp_w, afT, nT);

        const int blocksG = N_ROWS / 32;                // 3125, exact
        gather_kernel<<<blocksG, 256, 0, stream>>>(afT, nbr_idx, s, out);
    } else {
        const int blocksA = E_TOT / 128;
        edge_mlp_mfma_kernel<<<blocksA, 256, 0, stream>>>(nbr_fea, bpack, w2, b2, s);
        const int blocksB = (N_ROWS + 63) / 64;
        gather_transform_kernel<<<blocksB, 256, 0, stream>>>(atom_fea, nbr_idx, s, tp_w, out);
    }
}